// Round 4
// baseline (725.227 us; speedup 1.0000x reference)
//
#include <hip/hip_runtime.h>
#include <cstdint>
#include <cstddef>

// ---------------- problem dims ----------------
#define NB 4096   // batch
#define NE 768    // in features
#define NH 2048   // hidden
#define NKF 128   // GP feature dim
#define NC 200    // classes
#define NN 20     // inducing points per class
#define NITER_R 10  // iterations on G^4 (== 40 on G)

typedef __attribute__((ext_vector_type(8))) short s16x8;
typedef __attribute__((ext_vector_type(8))) unsigned short u16x8;
typedef __attribute__((ext_vector_type(4))) unsigned short u16x4;
typedef __attribute__((ext_vector_type(4))) float f32x4;

__device__ inline unsigned short f2bf(float x) {
  unsigned u = __builtin_bit_cast(unsigned, x);
  u += 0x7fffu + ((u >> 16) & 1u);
  return (unsigned short)(u >> 16);
}
__device__ inline float bf2f(unsigned short h) {
  return __builtin_bit_cast(float, (unsigned)h << 16);
}
__device__ inline float gelu_exact(float x) {
  return x * 0.5f * (1.0f + erff(x * 0.70710678118654752f));
}

// async global->LDS 16B/lane. lds base must be wave-uniform; HW writes base+lane*16.
__device__ inline void gl16(const unsigned short* g, unsigned short* l) {
  __builtin_amdgcn_global_load_lds(
      (const __attribute__((address_space(1))) unsigned int*)(uintptr_t)(g),
      (__attribute__((address_space(3))) unsigned int*)(uintptr_t)(l),
      16, 0, 0);
}

// ---------------- workspace layout (bytes) ----------------
constexpr size_t SZ_W1BF = (size_t)NH * NE * 2;
constexpr size_t SZ_W2BF = (size_t)NH * NH * 2;
constexpr size_t SZ_WPBF = (size_t)NKF * NH * 2;
constexpr size_t SZ_SLOT = (size_t)NB * NH * 2;  // 16.8 MB

constexpr size_t OFF_W1BF = 0;
constexpr size_t OFF_W2BF = OFF_W1BF + SZ_W1BF;
constexpr size_t OFF_WPBF = OFF_W2BF + SZ_W2BF;
constexpr size_t OFF_XBF  = OFF_WPBF + SZ_WPBF;  // slot A
constexpr size_t OFF_H2BF = OFF_XBF;             // gemm2 out (after gemm1 consumed Xbf)
constexpr size_t OFF_H1BF = OFF_XBF + SZ_SLOT;   // slot B
constexpr size_t OFF_H1N  = OFF_H1BF + SZ_SLOT;  // slot C
constexpr size_t OFF_HP   = OFF_H1N + SZ_SLOT;   // projection fp32 [NB][NKF]
constexpr size_t OFF_H2S  = OFF_HP + (size_t)NB * NKF * 4;  // |h|^2 per row
constexpr size_t OFF_PV   = OFF_H2S + (size_t)NB * 4;       // iter vectors + norm slots
constexpr size_t OFF_SINV = OFF_PV + (size_t)3 * 3 * 2048 * 4;
constexpr size_t OFF_Z2   = OFF_SINV + 256;
constexpr size_t OFF_LC   = OFF_Z2 + (size_t)NC * NN * 4;
constexpr size_t OFF_AL   = OFF_LC + (size_t)NC * NN * NN * 4;
constexpr size_t WS_NEED  = OFF_AL + (size_t)NC * NN * 4;

// --- gram-phase aliases (dead before the MLP writes these slots) ---
// slot A: W1T | Wp0 | G1a | G1b | Gp_acc(f32)
constexpr size_t GOFF_W1T   = OFF_XBF;                            // bf16 [768][2048]  3.0MB
constexpr size_t GOFF_WP0   = GOFF_W1T + (size_t)NE * NH * 2;     // bf16 [128][2048]  0.5MB
constexpr size_t GOFF_G1A   = GOFF_WP0 + (size_t)NKF * NH * 2;    // bf16 768^2        1.2MB
constexpr size_t GOFF_G1B   = GOFF_G1A + (size_t)NE * NE * 2;     // bf16 768^2        1.2MB
constexpr size_t GOFF_GPACC = GOFF_G1B + (size_t)NE * NE * 2;     // f32 128^2         64KB
static_assert(GOFF_GPACC + (size_t)NKF * NKF * 4 <= OFF_XBF + SZ_SLOT, "slotA overflow");
// slot B: W20 bf16 2048^2 (8.4MB)
constexpr size_t GOFF_W20 = OFF_H1BF;
// slot C: G2c / G2d ping-pong bf16 2048^2 each
constexpr size_t GOFF_G2C = OFF_H1N;
constexpr size_t GOFF_G2D = OFF_H1N + (size_t)NH * NH * 2;
// --- GP-phase aliases ---
constexpr size_t OFF_HPBF = OFF_H1BF;                          // bf16 [4096][128]
constexpr size_t OFF_ZPAD = OFF_H1BF + (size_t)NB * NKF * 2;   // bf16 [200][32][128]
constexpr size_t OFF_LGT  = OFF_H1N;                           // f32 [200][4096] logitsT

// ==================== helpers ====================
__global__ __launch_bounds__(256) void cast_bf(const float* __restrict__ in,
                                               unsigned short* __restrict__ out, int n) {
  for (int i = blockIdx.x * 256 + threadIdx.x; i < n; i += gridDim.x * 256)
    out[i] = f2bf(in[i]);
}

// transpose+cast: fp32 [R][C] -> bf16 [C][R]
__global__ __launch_bounds__(256) void transpose_cast(const float* __restrict__ in,
                                                      unsigned short* __restrict__ out,
                                                      int R, int C) {
  __shared__ float tile[64][65];
  int c0 = blockIdx.x * 64, r0 = blockIdx.y * 64;
  int tx = threadIdx.x & 63, ty = threadIdx.x >> 6;
  #pragma unroll
  for (int j = 0; j < 16; ++j) {
    int r = ty + j * 4;
    tile[r][tx] = in[(size_t)(r0 + r) * C + c0 + tx];
  }
  __syncthreads();
  #pragma unroll
  for (int j = 0; j < 16; ++j) {
    int cc = ty + j * 4;
    out[(size_t)(c0 + cc) * R + r0 + tx] = f2bf(tile[tx][cc]);
  }
}

// ==================== unnormalized power iteration on G^4/16 (bf16) ====================
// vb: [2 mats][2 ping-pong][2048] f32 ; slots: [2][16] f32 (||v_i||^2)
__global__ __launch_bounds__(256) void init_gram(float* __restrict__ vb,
                                                 float* __restrict__ slots) {
  int t = threadIdx.x;
  for (int i = t; i < 2 * 2 * 2048; i += 256) vb[i] = 0.0f;
  for (int i = t; i < 32; i += 256) slots[i] = 0.0f;
  __syncthreads();
  const int kd[2] = {NE, NH};
  for (int m = 0; m < 2; ++m)
    for (int k = t; k < kd[m]; k += 256) vb[(m * 2) * 2048 + k] = 1.0f;
}

__global__ __launch_bounds__(256) void gram_iter(const unsigned short* __restrict__ G1q,
                                                 const unsigned short* __restrict__ G2q,
                                                 float* __restrict__ vb,
                                                 float* __restrict__ slots, int iter) {
  int b = blockIdx.x, t = threadIdx.x;
  int m, r0, Kd;
  const unsigned short* G;
  if (b < 96) { m = 0; G = G1q; Kd = NE; r0 = b * 8; }
  else        { m = 1; G = G2q; Kd = NH; r0 = (b - 96) * 8; }

  const float* vin = vb + ((size_t)m * 2 + (iter & 1)) * 2048;
  float* vout      = vb + ((size_t)m * 2 + ((iter + 1) & 1)) * 2048;

  __shared__ float vs[2048];
  for (int k = t; k < Kd; k += 256) vs[k] = vin[k];
  __syncthreads();

  int w = t >> 6, lane = t & 63;
  float nrm = 0.f;
  #pragma unroll
  for (int rr = 0; rr < 2; ++rr) {
    int row = r0 + w * 2 + rr;
    const unsigned short* gr = G + (size_t)row * Kd;
    float s = 0.f;
    for (int k0 = lane * 8; k0 < Kd; k0 += 512) {
      u16x8 u = *(const u16x8*)(gr + k0);
      #pragma unroll
      for (int q = 0; q < 8; ++q) s += bf2f(u[q]) * vs[k0 + q];
    }
    for (int off = 32; off; off >>= 1) s += __shfl_down(s, off);
    if (lane == 0) { vout[row] = s; nrm += s * s; }
  }
  if (lane == 0) atomicAdd(&slots[m * 16 + iter + 1], nrm);
}

__global__ void finalize_sigma(const float* __restrict__ slots, float* __restrict__ sinv) {
  int m = threadIdx.x;
  if (m < 2) {
    // iterated matrix = G^4/16; lam(G^4) = 16*||v10||/||v9|| ; sigma = lam^(1/8)
    float lam4 = 16.0f * sqrtf(slots[m * 16 + NITER_R] / slots[m * 16 + NITER_R - 1]);
    sinv[m] = powf(lam4, -0.125f);
  }
}

// single-block power iteration on Gp (128x128 f32 in LDS), 40 iters -> sinv[2]
__global__ __launch_bounds__(256) void gp_power(const float* __restrict__ Gp,
                                                float* __restrict__ sinv) {
  __shared__ float Gs[NKF * NKF];
  __shared__ float v[NKF];
  __shared__ float r2[4];
  __shared__ float Ss[2];
  int t = threadIdx.x;
  for (int i = t; i < NKF * NKF; i += 256) Gs[i] = Gp[i];
  if (t < NKF) v[t] = 1.0f;
  __syncthreads();
  for (int it = 0; it < 40; ++it) {
    float s = 0.f;
    if (t < NKF) {
      const float* gr = &Gs[t * NKF];
      #pragma unroll 8
      for (int k = 0; k < NKF; ++k) s += gr[k] * v[k];
    }
    __syncthreads();
    if (t < NKF) v[t] = s;
    if (it >= 38) {
      float q = (t < NKF) ? s * s : 0.f;
      for (int off = 32; off; off >>= 1) q += __shfl_down(q, off);
      if ((t & 63) == 0) r2[t >> 6] = q;
      __syncthreads();
      if (t == 0) Ss[it - 38] = r2[0] + r2[1] + r2[2] + r2[3];
    }
    __syncthreads();
  }
  if (t == 0) sinv[2] = powf(Ss[1] / Ss[0], -0.25f);
}

__global__ __launch_bounds__(256) void scale_weights(const float* __restrict__ W1,
                                                     const float* __restrict__ W2,
                                                     const float* __restrict__ Wp,
                                                     const float* __restrict__ sinv,
                                                     unsigned short* __restrict__ W1bf,
                                                     unsigned short* __restrict__ W2bf,
                                                     unsigned short* __restrict__ Wpbf) {
  const int n1 = NH * NE, n2 = NH * NH;
  float s0 = sinv[0], s1 = sinv[1], s2 = sinv[2];
  int base = blockIdx.x * 2048;
  for (int i = threadIdx.x; i < 2048; i += 256) {
    int g = base + i;
    if (g < n1) {
      W1bf[g] = f2bf(W1[g] * s0);
    } else if (g < n1 + n2) {
      int q = g - n1; W2bf[q] = f2bf(W2[q] * s1);
    } else {
      int q = g - n1 - n2; Wpbf[q] = f2bf(Wp[q] * s2);
    }
  }
}

// ==================== layernorms ====================
__global__ __launch_bounds__(256) void ln_e(const float* __restrict__ X,
                                            const float* __restrict__ g,
                                            const float* __restrict__ b,
                                            unsigned short* __restrict__ out) {
  int wid = threadIdx.x >> 6, lane = threadIdx.x & 63;
  int row = blockIdx.x * 4 + wid;
  const float* xr = X + (size_t)row * NE;
  float4 v[3];
  float s = 0.f, sq = 0.f;
  #pragma unroll
  for (int j = 0; j < 3; ++j) {
    v[j] = *(const float4*)(xr + j * 256 + lane * 4);
    s += v[j].x + v[j].y + v[j].z + v[j].w;
    sq += v[j].x * v[j].x + v[j].y * v[j].y + v[j].z * v[j].z + v[j].w * v[j].w;
  }
  for (int off = 32; off; off >>= 1) { s += __shfl_down(s, off); sq += __shfl_down(sq, off); }
  s = __shfl(s, 0); sq = __shfl(sq, 0);
  float mean = s * (1.0f / NE);
  float var = sq * (1.0f / NE) - mean * mean;
  float rstd = rsqrtf(var + 1e-5f);
  unsigned short* orow = out + (size_t)row * NE;
  #pragma unroll
  for (int j = 0; j < 3; ++j) {
    int e0 = j * 256 + lane * 4;
    float4 gg = *(const float4*)(g + e0);
    float4 bb = *(const float4*)(b + e0);
    u16x4 o;
    o[0] = f2bf((v[j].x - mean) * rstd * gg.x + bb.x);
    o[1] = f2bf((v[j].y - mean) * rstd * gg.y + bb.y);
    o[2] = f2bf((v[j].z - mean) * rstd * gg.z + bb.z);
    o[3] = f2bf((v[j].w - mean) * rstd * gg.w + bb.w);
    *(u16x4*)(orow + e0) = o;
  }
}

__global__ __launch_bounds__(256) void ln_h(const unsigned short* __restrict__ X,
                                            const float* __restrict__ g,
                                            const float* __restrict__ b,
                                            unsigned short* __restrict__ out) {
  int wid = threadIdx.x >> 6, lane = threadIdx.x & 63;
  int row = blockIdx.x * 4 + wid;
  const unsigned short* xr = X + (size_t)row * NH;
  float xv[32];
  float s = 0.f, sq = 0.f;
  #pragma unroll
  for (int j = 0; j < 4; ++j) {
    u16x8 u = *(const u16x8*)(xr + j * 512 + lane * 8);
    #pragma unroll
    for (int q = 0; q < 8; ++q) {
      float x = bf2f(u[q]);
      xv[j * 8 + q] = x; s += x; sq += x * x;
    }
  }
  for (int off = 32; off; off >>= 1) { s += __shfl_down(s, off); sq += __shfl_down(sq, off); }
  s = __shfl(s, 0); sq = __shfl(sq, 0);
  float mean = s * (1.0f / NH);
  float var = sq * (1.0f / NH) - mean * mean;
  float rstd = rsqrtf(var + 1e-5f);
  unsigned short* orow = out + (size_t)row * NH;
  #pragma unroll
  for (int j = 0; j < 4; ++j) {
    int e0 = j * 512 + lane * 8;
    float4 ga = *(const float4*)(g + e0);
    float4 gb = *(const float4*)(g + e0 + 4);
    float4 ba = *(const float4*)(b + e0);
    float4 bb = *(const float4*)(b + e0 + 4);
    u16x8 o;
    o[0] = f2bf((xv[j*8+0] - mean) * rstd * ga.x + ba.x);
    o[1] = f2bf((xv[j*8+1] - mean) * rstd * ga.y + ba.y);
    o[2] = f2bf((xv[j*8+2] - mean) * rstd * ga.z + ba.z);
    o[3] = f2bf((xv[j*8+3] - mean) * rstd * ga.w + ba.w);
    o[4] = f2bf((xv[j*8+4] - mean) * rstd * gb.x + bb.x);
    o[5] = f2bf((xv[j*8+5] - mean) * rstd * gb.y + bb.y);
    o[6] = f2bf((xv[j*8+6] - mean) * rstd * gb.z + bb.z);
    o[7] = f2bf((xv[j*8+7] - mean) * rstd * gb.w + bb.w);
    *(u16x8*)(orow + e0) = o;
  }
}

// ==================== bf16 MFMA GEMM (NT): C = A[M,K] * B[N,K]^T ====================
// m97 structure: 128x128 tile, BK=32, linear LDS [128][32], global_load_lds 16B staging.
// EPI 0: gelu(acc+bias) -> bf16.  EPI 1: atomicAdd fp32 (split-K).  EPI 3: bf16 * cscale.
template <int EPI>
__global__ __launch_bounds__(256) void gemm_nt(const unsigned short* __restrict__ A,
                                               const unsigned short* __restrict__ Bm,
                                               const float* __restrict__ bias,
                                               void* __restrict__ Cout,
                                               int M, int Nn, int Kk, int KCH,
                                               float cscale) {
  __shared__ __align__(16) unsigned short As[128 * 32];
  __shared__ __align__(16) unsigned short Bs[128 * 32];
  int t = threadIdx.x;
  int bm0 = blockIdx.x * 128, bn0 = blockIdx.y * 128;
  int wid = t >> 6, lane = t & 63;
  int wm = wid >> 1, wn = wid & 1;

  int kb = 0, ke = Kk;
  if (KCH > 0) { kb = blockIdx.z * KCH; ke = kb + KCH; }

  f32x4 acc[4][4] = {};

  int lrow = t >> 2;         // 0..63 (row within half-tile for staging)
  int lk8 = (t & 3) * 8;     // k-chunk within row
  const unsigned short* Ag = A + (size_t)(bm0 + lrow) * Kk + lk8;
  const unsigned short* Bg = Bm + (size_t)(bn0 + lrow) * Kk + lk8;
  // wave-uniform LDS staging bases: wave w covers rows [w*16, w*16+16) and [64+w*16, ...)
  unsigned short* AsW0 = As + wid * 512;
  unsigned short* AsW1 = As + 2048 + wid * 512;
  unsigned short* BsW0 = Bs + wid * 512;
  unsigned short* BsW1 = Bs + 2048 + wid * 512;

  int arow = wm * 64 + (lane & 15);
  int brow = wn * 64 + (lane & 15);
  int kfr = (lane >> 4) * 8;

  for (int ks = kb; ks < ke; ks += 32) {
    if (ks > kb) __syncthreads();  // prior fragment reads done before overwrite
    gl16(Ag + ks, AsW0);
    gl16(Ag + (size_t)64 * Kk + ks, AsW1);
    gl16(Bg + ks, BsW0);
    gl16(Bg + (size_t)64 * Kk + ks, BsW1);
    __syncthreads();               // drains vmcnt -> staged data visible
    s16x8 af[4], bfr[4];
    #pragma unroll
    for (int i = 0; i < 4; ++i) af[i] = *(const s16x8*)&As[(arow + i * 16) * 32 + kfr];
    #pragma unroll
    for (int j = 0; j < 4; ++j) bfr[j] = *(const s16x8*)&Bs[(brow + j * 16) * 32 + kfr];
    #pragma unroll
    for (int i = 0; i < 4; ++i)
      #pragma unroll
      for (int j = 0; j < 4; ++j)
        acc[i][j] = __builtin_amdgcn_mfma_f32_16x16x32_bf16(af[i], bfr[j], acc[i][j], 0, 0, 0);
  }

  // D layout: row = (lane>>4)*4 + reg, col = lane&15
  int crow0 = bm0 + wm * 64 + (lane >> 4) * 4;
  int ccol0 = bn0 + wn * 64 + (lane & 15);
  if constexpr (EPI == 0) {
    unsigned short* C = (unsigned short*)Cout;
    #pragma unroll
    for (int i = 0; i < 4; ++i) {
      #pragma unroll
      for (int j = 0; j < 4; ++j) {
        int col = ccol0 + j * 16;
        float bb = bias[col];
        #pragma unroll
        for (int r = 0; r < 4; ++r) {
          int row = crow0 + i * 16 + r;
          float x = acc[i][j][r] + bb;
          C[(size_t)row * Nn + col] = f2bf(gelu_exact(x));
        }
      }
    }
  } else if constexpr (EPI == 1) {
    float* C = (float*)Cout;
    #pragma unroll
    for (int i = 0; i < 4; ++i)
      #pragma unroll
      for (int j = 0; j < 4; ++j) {
        int col = ccol0 + j * 16;
        #pragma unroll
        for (int r = 0; r < 4; ++r) {
          int row = crow0 + i * 16 + r;
          atomicAdd(&C[(size_t)row * Nn + col], acc[i][j][r]);
        }
      }
  } else {
    unsigned short* C = (unsigned short*)Cout;
    #pragma unroll
    for (int i = 0; i < 4; ++i)
      #pragma unroll
      for (int j = 0; j < 4; ++j) {
        int col = ccol0 + j * 16;
        #pragma unroll
        for (int r = 0; r < 4; ++r) {
          int row = crow0 + i * 16 + r;
          C[(size_t)row * Nn + col] = f2bf(acc[i][j][r] * cscale);
        }
      }
  }
}

// add bias, |h|^2 per row, write bf16 h. one wave per row.
__global__ __launch_bounds__(256) void finish_proj(const float* __restrict__ Hp,
                                                   const float* __restrict__ bp,
                                                   unsigned short* __restrict__ Hpb,
                                                   float* __restrict__ h2) {
  int wid = threadIdx.x >> 6, lane = threadIdx.x & 63;
  int row = blockIdx.x * 4 + wid;
  const float* r = Hp + (size_t)row * NKF;
  float x0 = r[lane] + bp[lane];
  float x1 = r[lane + 64] + bp[lane + 64];
  float s = x0 * x0 + x1 * x1;
  for (int off = 32; off; off >>= 1) s += __shfl_down(s, off);
  unsigned short* hb = Hpb + (size_t)row * NKF;
  hb[lane] = f2bf(x0);
  hb[lane + 64] = f2bf(x1);
  if (lane == 0) h2[row] = s;
}

// ==================== GP prep: z2, k_zz Cholesky, alpha, z bf16 padded ====================
__global__ __launch_bounds__(128) void gp_prep(const float* __restrict__ z,
                                               const float* __restrict__ vm,
                                               const float* __restrict__ ll,
                                               float* __restrict__ z2g,
                                               float* __restrict__ Lg,
                                               float* __restrict__ alphag,
                                               unsigned short* __restrict__ zpad) {
  int c = blockIdx.x, t = threadIdx.x;
  __shared__ float zc[NN * NKF];
  __shared__ float Amat[NN][NN + 1];
  __shared__ float z2s[NN], ys[NN], al[NN];
  const float* zcg = z + (size_t)c * NN * NKF;
  for (int i = t; i < NN * NKF; i += 128) zc[i] = zcg[i];
  __syncthreads();
  if (t < NN) {
    float s = 0.f;
    for (int k = 0; k < NKF; ++k) { float v = zc[t * NKF + k]; s += v * v; }
    z2s[t] = s;
    z2g[c * NN + t] = s;
  }
  __syncthreads();
  float inv2 = 0.5f * expf(-2.0f * ll[0]);
  for (int e = t; e < NN * NN; e += 128) {
    int n = e / NN, m = e % NN;
    float d = 0.f;
    for (int k = 0; k < NKF; ++k) d += zc[n * NKF + k] * zc[m * NKF + k];
    float d2 = fmaxf(z2s[n] + z2s[m] - 2.0f * d, 0.0f);
    float v = expf(-d2 * inv2);
    if (n == m) v += 1e-4f;
    Amat[n][m] = v;
  }
  __syncthreads();
  for (int j = 0; j < NN; ++j) {
    if (t == 0) {
      float s = Amat[j][j];
      for (int p = 0; p < j; ++p) s -= Amat[j][p] * Amat[j][p];
      Amat[j][j] = sqrtf(s);
    }
    __syncthreads();
    if (t > j && t < NN) {
      float s = Amat[t][j];
      for (int p = 0; p < j; ++p) s -= Amat[t][p] * Amat[j][p];
      Amat[t][j] = s / Amat[j][j];
    }
    __syncthreads();
  }
  if (t == 0) {
    const float* mc = vm + c * NN;
    for (int n = 0; n < NN; ++n) {
      float s = mc[n];
      for (int m = 0; m < n; ++m) s -= Amat[n][m] * ys[m];
      ys[n] = s / Amat[n][n];
    }
    for (int n = NN - 1; n >= 0; --n) {
      float s = ys[n];
      for (int m = n + 1; m < NN; ++m) s -= Amat[m][n] * al[m];
      al[n] = s / Amat[n][n];
    }
  }
  __syncthreads();
  for (int e = t; e < NN * NN; e += 128) {
    int n = e / NN, m = e % NN;
    Lg[(size_t)c * NN * NN + e] = (m <= n) ? Amat[n][m] : 0.0f;
  }
  if (t < NN) alphag[c * NN + t] = al[t];
  unsigned short* zp = zpad + (size_t)c * 32 * NKF;
  for (int i = t; i < 32 * NKF; i += 128) {
    int n = i >> 7;
    zp[i] = (n < NN) ? f2bf(zc[n * NKF + (i & 127)]) : (unsigned short)0;
  }
}

// ==================== GP main: MFMA k_xz + logits + uncertainty ====================
__global__ __launch_bounds__(256) void gp_main(const unsigned short* __restrict__ Hpb,
                                               const float* __restrict__ h2g,
                                               const unsigned short* __restrict__ zpad,
                                               const float* __restrict__ z2g,
                                               const float* __restrict__ Lg,
                                               const float* __restrict__ alphag,
                                               const float* __restrict__ ll,
                                               float* __restrict__ logitsT,
                                               float* __restrict__ unc) {
  int c = blockIdx.y, b0 = blockIdx.x * 256, t = threadIdx.x;
  int w = t >> 6, lane = t & 63;
  __shared__ __align__(16) unsigned short zs[32 * 136];
  __shared__ float kxs[256][21];
  __shared__ float Ls[NN][21];
  __shared__ float z2s[32], al[NN], ht2[256];

  {
    const unsigned short* zp = zpad + (size_t)c * 32 * NKF;
    int n = t >> 3, k = (t & 7) * 16;
    u16x8 a = *(const u16x8*)(zp + n * NKF + k);
    u16x8 b = *(const u16x8*)(zp + n * NKF + k + 8);
    *(u16x8*)&zs[n * 136 + k] = a;
    *(u16x8*)&zs[n * 136 + k + 8] = b;
  }
  for (int i = t; i < NN * NN; i += 256) Ls[i / NN][i % NN] = Lg[(size_t)c * NN * NN + i];
  if (t < 32) z2s[t] = (t < NN) ? z2g[c * NN + t] : 0.f;
  if (t < NN) al[t] = alphag[c * NN + t];
  ht2[t] = h2g[b0 + t];
  float inv2 = 0.5f * __expf(-2.0f * ll[0]);
  __syncthreads();

  f32x4 acc[4][2] = {};
  const unsigned short* hbase = Hpb + (size_t)(b0 + w * 64 + (lane & 15)) * NKF + (lane >> 4) * 8;
  #pragma unroll
  for (int ks = 0; ks < 4; ++ks) {
    s16x8 af[4], bfr[2];
    #pragma unroll
    for (int i = 0; i < 4; ++i) af[i] = *(const s16x8*)(hbase + (size_t)i * 16 * NKF + ks * 32);
    #pragma unroll
    for (int j = 0; j < 2; ++j)
      bfr[j] = *(const s16x8*)&zs[(j * 16 + (lane & 15)) * 136 + ks * 32 + (lane >> 4) * 8];
    #pragma unroll
    for (int i = 0; i < 4; ++i)
      #pragma unroll
      for (int j = 0; j < 2; ++j)
        acc[i][j] = __builtin_amdgcn_mfma_f32_16x16x32_bf16(af[i], bfr[j], acc[i][j], 0, 0, 0);
  }

  #pragma unroll
  for (int i = 0; i < 4; ++i)
    #pragma unroll
    for (int j = 0; j < 2; ++j) {
      int col = j * 16 + (lane & 15);
      #pragma unroll
      for (int r = 0; r < 4; ++r) {
        int rl = w * 64 + i * 16 + (lane >> 4) * 4 + r;
        float d2 = fmaxf(ht2[rl] + z2s[col] - 2.0f * acc[i][j][r], 0.0f);
        float kx = __expf(-d2 * inv2);
        if (col < NN) kxs[rl][col] = kx;
      }
    }
  __syncthreads();

  float kr[NN];
  #pragma unroll
  for (int n = 0; n < NN; ++n) kr[n] = kxs[t][n];
  float lg = 0.f;
  #pragma unroll
  for (int n = 0; n < NN; ++n) lg += kr[n] * al[n];
  logitsT[(size_t)c * NB + b0 + t] = lg;

  float vsum = 0.f;
  #pragma unroll
  for (int n = 0; n < NN; ++n) {
    float s = kr[n];
    #pragma unroll
    for (int m = 0; m < NN; ++m)
      if (m < n) s -= Ls[n][m] * kr[m];
    s /= Ls[n][n];
    kr[n] = s;
    vsum += s * s;
  }
  atomicAdd(&unc[b0 + t], fmaxf(1.0f - vsum, 0.0f) * (1.0f / NC));
}

// ==================== transpose + softmax: logitsT [C][B] -> probs/logits [B][C] ====================
__global__ __launch_bounds__(256) void softmax_t(const float* __restrict__ logitsT,
                                                 float* __restrict__ probs,
                                                 float* __restrict__ logits_out) {
  int b0 = blockIdx.x * 64, t = threadIdx.x;
  __shared__ float tile[NC][65];
  __shared__ float redmx[4][64], redsm[4][64], mxs[64], invs[64];
  for (int i = t; i < NC * 64; i += 256) {
    int cc = i >> 6, j = i & 63;
    tile[cc][j] = logitsT[(size_t)cc * NB + b0 + j];
  }
  __syncthreads();
  int j = t & 63, p = t >> 6;
  float mx = -1e30f;
  for (int cc = p * 50; cc < p * 50 + 50; ++cc) mx = fmaxf(mx, tile[cc][j]);
  redmx[p][j] = mx;
  __syncthreads();
  if (p == 0) mxs[j] = fmaxf(fmaxf(redmx[0][j], redmx[1][j]), fmaxf(redmx[2][j], redmx[3][j]));
  __syncthreads();
  float m2 = mxs[j], sm = 0.f;
  for (int cc = p * 50; cc < p * 50 + 50; ++cc) sm += __expf(tile[cc][j] - m2);
  redsm[p][j] = sm;
  __syncthreads();
  if (p == 0) invs[j] = 1.0f / (redsm[0][j] + redsm[1][j] + redsm[2][j] + redsm[3][j]);
  __syncthreads();
  for (int i = t; i < 64 * NC; i += 256) {
    int jj = i / NC, cc = i % NC;
    float lv = tile[cc][jj];
    size_t o = (size_t)(b0 + jj) * NC + cc;
    probs[o] = __expf(lv - mxs[jj]) * invs[jj];
    logits_out[o] = lv;
  }
}

// ==================== launch ====================
extern "C" void kernel_launch(void* const* d_in, const int* in_sizes, int n_in,
                              void* d_out, int out_size, void* d_ws, size_t ws_size,
                              hipStream_t stream) {
  if (ws_size < WS_NEED) return;

  const float* X   = (const float*)d_in[0];
  const float* g1  = (const float*)d_in[1];
  const float* be1 = (const float*)d_in[2];
  const float* W1  = (const float*)d_in[3];
  const float* b1  = (const float*)d_in[4];
  const float* g2  = (const float*)d_in[5];
  const float* be2 = (const float*)d_in[6];
  const float* W2  = (const float*)d_in[7];
  const float* b2  = (const float*)d_in[8];
  const float* Wp  = (const float*)d_in[9];
  const float* bp  = (const float*)d_in[10];
  const float* ll  = (const float*)d_in[11];
  const float* Z   = (const float*)d_in[12];
  const float* VM  = (const float*)d_in[13];

  char* ws = (char*)d_ws;
  unsigned short* W1bf = (unsigned short*)(ws + OFF_W1BF);
  unsigned short* W2bf = (unsigned short*)(ws + OFF_W2BF);
  unsigned short* Wpbf = (unsigned short*)(ws + OFF_WPBF);
  unsigned short* Xbf  = (unsigned short*)(ws + OFF_XBF);
  unsigned short* H2bf = (unsigned short*)(ws + OFF_H2BF);
  unsigned short* H1bf = (unsigned short*)(ws + OFF_H1BF);
  unsigned short* H1n  = (unsigned short*)(ws + OFF_H1N);
  float* Hp    = (float*)(ws + OFF_HP);
  float* h2s   = (float*)(ws + OFF_H2S);
  float* vb    = (float*)(ws + OFF_PV);
  float* slots = vb + 2 * 2 * 2048;
  float* sinv  = (float*)(ws + OFF_SINV);
  float* z2g   = (float*)(ws + OFF_Z2);
  float* Lg    = (float*)(ws + OFF_LC);
  float* alphag= (float*)(ws + OFF_AL);

  // gram-phase aliases
  unsigned short* W1T  = (unsigned short*)(ws + GOFF_W1T);
  unsigned short* Wp0  = (unsigned short*)(ws + GOFF_WP0);
  unsigned short* G1a  = (unsigned short*)(ws + GOFF_G1A);
  unsigned short* G1b  = (unsigned short*)(ws + GOFF_G1B);
  float*          Gpacc= (float*)(ws + GOFF_GPACC);
  unsigned short* W20  = (unsigned short*)(ws + GOFF_W20);
  unsigned short* G2c  = (unsigned short*)(ws + GOFF_G2C);
  unsigned short* G2d  = (unsigned short*)(ws + GOFF_G2D);
  // GP-phase aliases
  unsigned short* Hpb  = (unsigned short*)(ws + OFF_HPBF);
  unsigned short* zpad = (unsigned short*)(ws + OFF_ZPAD);
  float* logitsT = (float*)(ws + OFF_LGT);

  float* out    = (float*)d_out;
  float* logits = out + (size_t)NB * NC;
  float* unc    = out + (size_t)2 * NB * NC;

  hipMemsetAsync(Hp, 0, (size_t)NB * NKF * 4, stream);
  hipMemsetAsync(unc, 0, (size_t)NB * 4, stream);
  hipMemsetAsync(Gpacc, 0, (size_t)NKF * NKF * 4, stream);

  // ---- spectral norms ----
  cast_bf<<<dim3(2048), 256, 0, stream>>>(W2, W20, NH * NH);
  cast_bf<<<dim3(128), 256, 0, stream>>>(Wp, Wp0, NKF * NH);
  transpose_cast<<<dim3(NE / 64, NH / 64), 256, 0, stream>>>(W1, W1T, NH, NE);
  // Gp = Wp*Wp^T (split-K fp32 atomics), then all 40 power iters in one block
  gemm_nt<1><<<dim3(1, 1, 16), 256, 0, stream>>>(Wp0, Wp0, nullptr, (void*)Gpacc, NKF, NKF, NH, NH / 16, 1.0f);
  gp_power<<<dim3(1), 256, 0, stream>>>(Gpacc, sinv);
  // G -> G^2 -> G^4/16 for W1 (768^2) and W2 (2048^2)
  gemm_nt<3><<<dim3(NE / 128, NE / 128), 256, 0, stream>>>(W1T, W1T, nullptr, (void*)G1a, NE, NE, NH, 0, 1.0f);
  gemm_nt<3><<<dim3(NH / 128, NH / 128), 256, 0, stream>>>(W20, W20, nullptr, (void*)G2c, NH, NH, NH, 0, 1.0f);
  gemm_nt<3><<<dim3(NE / 128, NE / 128), 256, 0, stream>>>(G1a, G1a, nullptr, (void*)G1b, NE, NE, NE, 0, 1.0f);
  gemm_nt<3><<<dim3(NH / 128, NH / 128), 256, 0, stream>>>(G2c, G2c, nullptr, (void*)G2d, NH, NH, NH, 0, 1.0f);
  gemm_nt<3><<<dim3(NE / 128, NE / 128), 256, 0, stream>>>(G1b, G1b, nullptr, (void*)G1a, NE, NE, NE, 0, 0.0625f);
  gemm_nt<3><<<dim3(NH / 128, NH / 128), 256, 0, stream>>>(G2d, G2d, nullptr, (void*)G2c, NH, NH, NH, 0, 0.0625f);
  init_gram<<<dim3(1), 256, 0, stream>>>(vb, slots);
  for (int i = 0; i < NITER_R; ++i)
    gram_iter<<<dim3(352), 256, 0, stream>>>(G1a, G2c, vb, slots, i);
  finalize_sigma<<<dim3(1), 64, 0, stream>>>(slots, sinv);
  scale_weights<<<dim3(2944), 256, 0, stream>>>(W1, W2, Wp, sinv, W1bf, W2bf, Wpbf);

  // ---- MLP ----
  ln_e<<<dim3(NB / 4), 256, 0, stream>>>(X, g1, be1, Xbf);
  gemm_nt<0><<<dim3(NB / 128, NH / 128), 256, 0, stream>>>(Xbf, W1bf, b1, (void*)H1bf, NB, NH, NE, 0, 1.0f);
  ln_h<<<dim3(NB / 4), 256, 0, stream>>>(H1bf, g2, be2, H1n);
  gemm_nt<0><<<dim3(NB / 128, NH / 128), 256, 0, stream>>>(H1n, W2bf, b2, (void*)H2bf, NB, NH, NH, 0, 1.0f);
  gemm_nt<1><<<dim3(NB / 128, 1, 8), 256, 0, stream>>>(H2bf, Wpbf, bp, (void*)Hp, NB, NKF, NH, NH / 8, 1.0f);
  finish_proj<<<dim3(NB / 4), 256, 0, stream>>>(Hp, bp, Hpb, h2s);

  // ---- GP head ----
  gp_prep<<<dim3(NC), 128, 0, stream>>>(Z, VM, ll, z2g, Lg, alphag, zpad);
  gp_main<<<dim3(NB / 256, NC), 256, 0, stream>>>(Hpb, h2s, zpad, z2g, Lg, alphag, ll, logitsT, unc);
  softmax_t<<<dim3(NB / 64), 256, 0, stream>>>(logitsT, out, logits);
}

// Round 5
// 609.968 us; speedup vs baseline: 1.1890x; 1.1890x over previous
//
#include <hip/hip_runtime.h>
#include <cstdint>
#include <cstddef>

// ---------------- problem dims ----------------
#define NB 4096   // batch
#define NE 768    // in features
#define NH 2048   // hidden
#define NKF 128   // GP feature dim
#define NC 200    // classes
#define NN 20     // inducing points per class
#define NITER_R 10  // iterations on G^4 (== 40 on G)

typedef __attribute__((ext_vector_type(8))) short s16x8;
typedef __attribute__((ext_vector_type(8))) unsigned short u16x8;
typedef __attribute__((ext_vector_type(4))) unsigned short u16x4;
typedef __attribute__((ext_vector_type(4))) float f32x4;

__device__ inline unsigned short f2bf(float x) {
  unsigned u = __builtin_bit_cast(unsigned, x);
  u += 0x7fffu + ((u >> 16) & 1u);
  return (unsigned short)(u >> 16);
}
__device__ inline float bf2f(unsigned short h) {
  return __builtin_bit_cast(float, (unsigned)h << 16);
}
__device__ inline float gelu_exact(float x) {
  return x * 0.5f * (1.0f + erff(x * 0.70710678118654752f));
}

// async global->LDS 16B/lane. lds base must be wave-uniform; HW writes base+lane*16.
__device__ inline void gl16(const unsigned short* g, unsigned short* l) {
  __builtin_amdgcn_global_load_lds(
      (const __attribute__((address_space(1))) unsigned int*)(uintptr_t)(g),
      (__attribute__((address_space(3))) unsigned int*)(uintptr_t)(l),
      16, 0, 0);
}

// ---------------- workspace layout (bytes) ----------------
constexpr size_t SZ_W1BF = (size_t)NH * NE * 2;
constexpr size_t SZ_W2BF = (size_t)NH * NH * 2;
constexpr size_t SZ_WPBF = (size_t)NKF * NH * 2;
constexpr size_t SZ_SLOT = (size_t)NB * NH * 2;  // 16.8 MB

constexpr size_t OFF_W1BF = 0;
constexpr size_t OFF_W2BF = OFF_W1BF + SZ_W1BF;
constexpr size_t OFF_WPBF = OFF_W2BF + SZ_W2BF;
constexpr size_t OFF_XBF  = OFF_WPBF + SZ_WPBF;  // slot A
constexpr size_t OFF_H2BF = OFF_XBF;             // gemm2 out (after gemm1 consumed Xbf)
constexpr size_t OFF_H1BF = OFF_XBF + SZ_SLOT;   // slot B
constexpr size_t OFF_H1N  = OFF_H1BF + SZ_SLOT;  // slot C
constexpr size_t OFF_HP   = OFF_H1N + SZ_SLOT;   // projection fp32 [NB][NKF]
constexpr size_t OFF_H2S  = OFF_HP + (size_t)NB * NKF * 4;  // |h|^2 per row
constexpr size_t OFF_PV   = OFF_H2S + (size_t)NB * 4;       // iter vectors + norm slots
constexpr size_t OFF_SINV = OFF_PV + (size_t)3 * 3 * 2048 * 4;
constexpr size_t OFF_Z2   = OFF_SINV + 256;
constexpr size_t OFF_LC   = OFF_Z2 + (size_t)NC * NN * 4;
constexpr size_t OFF_AL   = OFF_LC + (size_t)NC * NN * NN * 4;
constexpr size_t WS_NEED  = OFF_AL + (size_t)NC * NN * 4;

// --- gram-phase aliases (dead before the MLP writes these slots) ---
constexpr size_t GOFF_W1T   = OFF_XBF;                            // bf16 [768][2048]
constexpr size_t GOFF_WP0   = GOFF_W1T + (size_t)NE * NH * 2;     // bf16 [128][2048]
constexpr size_t GOFF_G1A   = GOFF_WP0 + (size_t)NKF * NH * 2;    // bf16 768^2
constexpr size_t GOFF_G1B   = GOFF_G1A + (size_t)NE * NE * 2;     // bf16 768^2
constexpr size_t GOFF_GPACC = GOFF_G1B + (size_t)NE * NE * 2;     // f32 128^2
static_assert(GOFF_GPACC + (size_t)NKF * NKF * 4 <= OFF_XBF + SZ_SLOT, "slotA overflow");
constexpr size_t GOFF_W20 = OFF_H1BF;                             // bf16 2048^2
constexpr size_t GOFF_G2C = OFF_H1N;                              // bf16 2048^2
constexpr size_t GOFF_G2D = OFF_H1N + (size_t)NH * NH * 2;        // bf16 2048^2
// --- GP-phase aliases ---
constexpr size_t OFF_HPBF = OFF_H1BF;                          // bf16 [4096][128]
constexpr size_t OFF_ZPAD = OFF_H1BF + (size_t)NB * NKF * 2;   // bf16 [200][32][128]
constexpr size_t OFF_LGT  = OFF_H1N;                           // f32 [200][4096] logitsT
constexpr size_t OFF_VART = OFF_LGT + (size_t)NC * NB * 4;     // f32 [200][4096] var_c
static_assert(OFF_VART + (size_t)NC * NB * 4 <= OFF_H1N + SZ_SLOT, "slotC overflow");

// ==================== helpers ====================
__global__ __launch_bounds__(256) void cast_bf(const float* __restrict__ in,
                                               unsigned short* __restrict__ out, int n) {
  for (int i = blockIdx.x * 256 + threadIdx.x; i < n; i += gridDim.x * 256)
    out[i] = f2bf(in[i]);
}

// transpose+cast: fp32 [R][C] -> bf16 [C][R]
__global__ __launch_bounds__(256) void transpose_cast(const float* __restrict__ in,
                                                      unsigned short* __restrict__ out,
                                                      int R, int C) {
  __shared__ float tile[64][65];
  int c0 = blockIdx.x * 64, r0 = blockIdx.y * 64;
  int tx = threadIdx.x & 63, ty = threadIdx.x >> 6;
  #pragma unroll
  for (int j = 0; j < 16; ++j) {
    int r = ty + j * 4;
    tile[r][tx] = in[(size_t)(r0 + r) * C + c0 + tx];
  }
  __syncthreads();
  #pragma unroll
  for (int j = 0; j < 16; ++j) {
    int cc = ty + j * 4;
    out[(size_t)(c0 + cc) * R + r0 + tx] = f2bf(tile[tx][cc]);
  }
}

// ==================== unnormalized power iteration on G^4/16 (bf16) ====================
__global__ __launch_bounds__(256) void init_gram(float* __restrict__ vb,
                                                 float* __restrict__ slots) {
  int t = threadIdx.x;
  for (int i = t; i < 2 * 2 * 2048; i += 256) vb[i] = 0.0f;
  for (int i = t; i < 32; i += 256) slots[i] = 0.0f;
  __syncthreads();
  const int kd[2] = {NE, NH};
  for (int m = 0; m < 2; ++m)
    for (int k = t; k < kd[m]; k += 256) vb[(m * 2) * 2048 + k] = 1.0f;
}

__global__ __launch_bounds__(256) void gram_iter(const unsigned short* __restrict__ G1q,
                                                 const unsigned short* __restrict__ G2q,
                                                 float* __restrict__ vb,
                                                 float* __restrict__ slots, int iter) {
  int b = blockIdx.x, t = threadIdx.x;
  int m, r0, Kd;
  const unsigned short* G;
  if (b < 96) { m = 0; G = G1q; Kd = NE; r0 = b * 8; }
  else        { m = 1; G = G2q; Kd = NH; r0 = (b - 96) * 8; }

  const float* vin = vb + ((size_t)m * 2 + (iter & 1)) * 2048;
  float* vout      = vb + ((size_t)m * 2 + ((iter + 1) & 1)) * 2048;

  __shared__ float vs[2048];
  for (int k = t; k < Kd; k += 256) vs[k] = vin[k];
  __syncthreads();

  int w = t >> 6, lane = t & 63;
  float nrm = 0.f;
  #pragma unroll
  for (int rr = 0; rr < 2; ++rr) {
    int row = r0 + w * 2 + rr;
    const unsigned short* gr = G + (size_t)row * Kd;
    float s = 0.f;
    for (int k0 = lane * 8; k0 < Kd; k0 += 512) {
      u16x8 u = *(const u16x8*)(gr + k0);
      #pragma unroll
      for (int q = 0; q < 8; ++q) s += bf2f(u[q]) * vs[k0 + q];
    }
    for (int off = 32; off; off >>= 1) s += __shfl_down(s, off);
    if (lane == 0) { vout[row] = s; nrm += s * s; }
  }
  if (lane == 0) atomicAdd(&slots[m * 16 + iter + 1], nrm);
}

__global__ void finalize_sigma(const float* __restrict__ slots, float* __restrict__ sinv) {
  int m = threadIdx.x;
  if (m < 2) {
    float lam4 = 16.0f * sqrtf(slots[m * 16 + NITER_R] / slots[m * 16 + NITER_R - 1]);
    sinv[m] = powf(lam4, -0.125f);
  }
}

// power iteration on Gp (128x128 f32): G-block in REGISTERS per thread, conflict-free.
// thread t: rows rg..rg+3 (rg=4*(t&31)), k-slice ks=t>>5 (16 k's). 40 iters.
__global__ __launch_bounds__(256) void gp_power(const float* __restrict__ Gp,
                                                float* __restrict__ sinv) {
  __shared__ float v[NKF];
  __shared__ float pred[8][NKF];
  __shared__ float nacc[2];
  int t = threadIdx.x;
  int rg = (t & 31) * 4;
  int ks = t >> 5;
  f32x4 Greg[16];
  #pragma unroll
  for (int kk = 0; kk < 16; ++kk)
    Greg[kk] = *(const f32x4*)(Gp + (size_t)(ks * 16 + kk) * NKF + rg);  // symmetric: row k, cols rg..
  if (t < NKF) v[t] = 1.0f;
  __syncthreads();
  float s_last0 = 1.f, s_last1 = 1.f;
  for (int it = 0; it < 40; ++it) {
    f32x4 p = {0.f, 0.f, 0.f, 0.f};
    #pragma unroll
    for (int kq = 0; kq < 4; ++kq) {
      f32x4 vv = *(const f32x4*)&v[ks * 16 + kq * 4];
      p += Greg[kq * 4 + 0] * vv[0];
      p += Greg[kq * 4 + 1] * vv[1];
      p += Greg[kq * 4 + 2] * vv[2];
      p += Greg[kq * 4 + 3] * vv[3];
    }
    *(f32x4*)&pred[ks][rg] = p;
    __syncthreads();
    float s = 0.f;
    if (t < NKF) {
      #pragma unroll
      for (int q = 0; q < 8; ++q) s += pred[q][t];
      v[t] = s;  // safe: all phase-1 reads of old v completed before the barrier
    }
    if (it >= 38) {
      float q2 = (t < NKF) ? s * s : 0.f;
      #pragma unroll
      for (int off = 32; off; off >>= 1) q2 += __shfl_down(q2, off);
      if (t == 0) nacc[0] = q2;
      if (t == 64) nacc[1] = q2;
    }
    __syncthreads();
    if (it == 38 && t == 0) s_last0 = nacc[0] + nacc[1];
    if (it == 39 && t == 0) s_last1 = nacc[0] + nacc[1];
  }
  if (t == 0) sinv[2] = powf(s_last1 / s_last0, -0.25f);
}

__global__ __launch_bounds__(256) void scale_weights(const float* __restrict__ W1,
                                                     const float* __restrict__ W2,
                                                     const float* __restrict__ Wp,
                                                     const float* __restrict__ sinv,
                                                     unsigned short* __restrict__ W1bf,
                                                     unsigned short* __restrict__ W2bf,
                                                     unsigned short* __restrict__ Wpbf) {
  const int n1 = NH * NE, n2 = NH * NH;
  float s0 = sinv[0], s1 = sinv[1], s2 = sinv[2];
  int base = blockIdx.x * 2048;
  for (int i = threadIdx.x; i < 2048; i += 256) {
    int g = base + i;
    if (g < n1) {
      W1bf[g] = f2bf(W1[g] * s0);
    } else if (g < n1 + n2) {
      int q = g - n1; W2bf[q] = f2bf(W2[q] * s1);
    } else {
      int q = g - n1 - n2; Wpbf[q] = f2bf(Wp[q] * s2);
    }
  }
}

// ==================== layernorms ====================
__global__ __launch_bounds__(256) void ln_e(const float* __restrict__ X,
                                            const float* __restrict__ g,
                                            const float* __restrict__ b,
                                            unsigned short* __restrict__ out) {
  int wid = threadIdx.x >> 6, lane = threadIdx.x & 63;
  int row = blockIdx.x * 4 + wid;
  const float* xr = X + (size_t)row * NE;
  float4 v[3];
  float s = 0.f, sq = 0.f;
  #pragma unroll
  for (int j = 0; j < 3; ++j) {
    v[j] = *(const float4*)(xr + j * 256 + lane * 4);
    s += v[j].x + v[j].y + v[j].z + v[j].w;
    sq += v[j].x * v[j].x + v[j].y * v[j].y + v[j].z * v[j].z + v[j].w * v[j].w;
  }
  for (int off = 32; off; off >>= 1) { s += __shfl_down(s, off); sq += __shfl_down(sq, off); }
  s = __shfl(s, 0); sq = __shfl(sq, 0);
  float mean = s * (1.0f / NE);
  float var = sq * (1.0f / NE) - mean * mean;
  float rstd = rsqrtf(var + 1e-5f);
  unsigned short* orow = out + (size_t)row * NE;
  #pragma unroll
  for (int j = 0; j < 3; ++j) {
    int e0 = j * 256 + lane * 4;
    float4 gg = *(const float4*)(g + e0);
    float4 bb = *(const float4*)(b + e0);
    u16x4 o;
    o[0] = f2bf((v[j].x - mean) * rstd * gg.x + bb.x);
    o[1] = f2bf((v[j].y - mean) * rstd * gg.y + bb.y);
    o[2] = f2bf((v[j].z - mean) * rstd * gg.z + bb.z);
    o[3] = f2bf((v[j].w - mean) * rstd * gg.w + bb.w);
    *(u16x4*)(orow + e0) = o;
  }
}

__global__ __launch_bounds__(256) void ln_h(const unsigned short* __restrict__ X,
                                            const float* __restrict__ g,
                                            const float* __restrict__ b,
                                            unsigned short* __restrict__ out) {
  int wid = threadIdx.x >> 6, lane = threadIdx.x & 63;
  int row = blockIdx.x * 4 + wid;
  const unsigned short* xr = X + (size_t)row * NH;
  float xv[32];
  float s = 0.f, sq = 0.f;
  #pragma unroll
  for (int j = 0; j < 4; ++j) {
    u16x8 u = *(const u16x8*)(xr + j * 512 + lane * 8);
    #pragma unroll
    for (int q = 0; q < 8; ++q) {
      float x = bf2f(u[q]);
      xv[j * 8 + q] = x; s += x; sq += x * x;
    }
  }
  for (int off = 32; off; off >>= 1) { s += __shfl_down(s, off); sq += __shfl_down(sq, off); }
  s = __shfl(s, 0); sq = __shfl(sq, 0);
  float mean = s * (1.0f / NH);
  float var = sq * (1.0f / NH) - mean * mean;
  float rstd = rsqrtf(var + 1e-5f);
  unsigned short* orow = out + (size_t)row * NH;
  #pragma unroll
  for (int j = 0; j < 4; ++j) {
    int e0 = j * 512 + lane * 8;
    float4 ga = *(const float4*)(g + e0);
    float4 gb = *(const float4*)(g + e0 + 4);
    float4 ba = *(const float4*)(b + e0);
    float4 bb = *(const float4*)(b + e0 + 4);
    u16x8 o;
    o[0] = f2bf((xv[j*8+0] - mean) * rstd * ga.x + ba.x);
    o[1] = f2bf((xv[j*8+1] - mean) * rstd * ga.y + ba.y);
    o[2] = f2bf((xv[j*8+2] - mean) * rstd * ga.z + ba.z);
    o[3] = f2bf((xv[j*8+3] - mean) * rstd * ga.w + ba.w);
    o[4] = f2bf((xv[j*8+4] - mean) * rstd * gb.x + bb.x);
    o[5] = f2bf((xv[j*8+5] - mean) * rstd * gb.y + bb.y);
    o[6] = f2bf((xv[j*8+6] - mean) * rstd * gb.z + bb.z);
    o[7] = f2bf((xv[j*8+7] - mean) * rstd * gb.w + bb.w);
    *(u16x8*)(orow + e0) = o;
  }
}

// ==================== bf16 MFMA GEMM (NT), 2-phase double-buffered ====================
// 128x128 tile, BK=32, LDS [2][128][32], global_load_lds 16B staging of tile k+1
// overlapped with compute of tile k (T3-minimum schedule, one barrier per K-step).
// EPI 0: gelu(acc+bias)->bf16.  EPI 1: atomicAdd fp32 (split-K).  EPI 3: bf16*cscale.
template <int EPI>
__global__ __launch_bounds__(256) void gemm_nt(const unsigned short* __restrict__ A,
                                               const unsigned short* __restrict__ Bm,
                                               const float* __restrict__ bias,
                                               void* __restrict__ Cout,
                                               int M, int Nn, int Kk, int KCH,
                                               float cscale) {
  __shared__ __align__(16) unsigned short As[2][128 * 32];
  __shared__ __align__(16) unsigned short Bs[2][128 * 32];
  int t = threadIdx.x;
  int bm0 = blockIdx.x * 128, bn0 = blockIdx.y * 128;
  int wid = t >> 6, lane = t & 63;
  int wm = wid >> 1, wn = wid & 1;

  int kb = 0, ke = Kk;
  if (KCH > 0) { kb = blockIdx.z * KCH; ke = kb + KCH; }

  f32x4 acc[4][4] = {};

  int lrow = t >> 2;
  int lk8 = (t & 3) * 8;
  const unsigned short* Ag = A + (size_t)(bm0 + lrow) * Kk + lk8;
  const unsigned short* Bg = Bm + (size_t)(bn0 + lrow) * Kk + lk8;

  int arow = wm * 64 + (lane & 15);
  int brow = wn * 64 + (lane & 15);
  int kfr = (lane >> 4) * 8;

  #define STAGE(nb, koff)                                   \
    do {                                                    \
      gl16(Ag + (koff), &As[nb][wid * 512]);                \
      gl16(Ag + (size_t)64 * Kk + (koff), &As[nb][2048 + wid * 512]); \
      gl16(Bg + (koff), &Bs[nb][wid * 512]);                \
      gl16(Bg + (size_t)64 * Kk + (koff), &Bs[nb][2048 + wid * 512]); \
    } while (0)

  STAGE(0, kb);
  __syncthreads();
  int cb = 0;
  for (int ks = kb; ks < ke; ks += 32) {
    if (ks + 32 < ke) STAGE(cb ^ 1, ks + 32);
    s16x8 af[4], bfr[4];
    #pragma unroll
    for (int i = 0; i < 4; ++i) af[i] = *(const s16x8*)&As[cb][(arow + i * 16) * 32 + kfr];
    #pragma unroll
    for (int j = 0; j < 4; ++j) bfr[j] = *(const s16x8*)&Bs[cb][(brow + j * 16) * 32 + kfr];
    #pragma unroll
    for (int i = 0; i < 4; ++i)
      #pragma unroll
      for (int j = 0; j < 4; ++j)
        acc[i][j] = __builtin_amdgcn_mfma_f32_16x16x32_bf16(af[i], bfr[j], acc[i][j], 0, 0, 0);
    __syncthreads();   // drains this iter's STAGE loads + protects buffer swap
    cb ^= 1;
  }
  #undef STAGE

  // D layout: row = (lane>>4)*4 + reg, col = lane&15
  int crow0 = bm0 + wm * 64 + (lane >> 4) * 4;
  int ccol0 = bn0 + wn * 64 + (lane & 15);
  if constexpr (EPI == 0) {
    unsigned short* C = (unsigned short*)Cout;
    #pragma unroll
    for (int i = 0; i < 4; ++i) {
      #pragma unroll
      for (int j = 0; j < 4; ++j) {
        int col = ccol0 + j * 16;
        float bb = bias[col];
        #pragma unroll
        for (int r = 0; r < 4; ++r) {
          int row = crow0 + i * 16 + r;
          float x = acc[i][j][r] + bb;
          C[(size_t)row * Nn + col] = f2bf(gelu_exact(x));
        }
      }
    }
  } else if constexpr (EPI == 1) {
    float* C = (float*)Cout;
    #pragma unroll
    for (int i = 0; i < 4; ++i)
      #pragma unroll
      for (int j = 0; j < 4; ++j) {
        int col = ccol0 + j * 16;
        #pragma unroll
        for (int r = 0; r < 4; ++r) {
          int row = crow0 + i * 16 + r;
          atomicAdd(&C[(size_t)row * Nn + col], acc[i][j][r]);
        }
      }
  } else {
    unsigned short* C = (unsigned short*)Cout;
    #pragma unroll
    for (int i = 0; i < 4; ++i)
      #pragma unroll
      for (int j = 0; j < 4; ++j) {
        int col = ccol0 + j * 16;
        #pragma unroll
        for (int r = 0; r < 4; ++r) {
          int row = crow0 + i * 16 + r;
          C[(size_t)row * Nn + col] = f2bf(acc[i][j][r] * cscale);
        }
      }
  }
}

// add bias, |h|^2 per row, write bf16 h. one wave per row.
__global__ __launch_bounds__(256) void finish_proj(const float* __restrict__ Hp,
                                                   const float* __restrict__ bp,
                                                   unsigned short* __restrict__ Hpb,
                                                   float* __restrict__ h2) {
  int wid = threadIdx.x >> 6, lane = threadIdx.x & 63;
  int row = blockIdx.x * 4 + wid;
  const float* r = Hp + (size_t)row * NKF;
  float x0 = r[lane] + bp[lane];
  float x1 = r[lane + 64] + bp[lane + 64];
  float s = x0 * x0 + x1 * x1;
  for (int off = 32; off; off >>= 1) s += __shfl_down(s, off);
  unsigned short* hb = Hpb + (size_t)row * NKF;
  hb[lane] = f2bf(x0);
  hb[lane + 64] = f2bf(x1);
  if (lane == 0) h2[row] = s;
}

// ==================== GP prep: z2, k_zz Cholesky, alpha, L^-1, z bf16 padded ====================
__global__ __launch_bounds__(128) void gp_prep(const float* __restrict__ z,
                                               const float* __restrict__ vm,
                                               const float* __restrict__ ll,
                                               float* __restrict__ z2g,
                                               float* __restrict__ Lig,
                                               float* __restrict__ alphag,
                                               unsigned short* __restrict__ zpad) {
  int c = blockIdx.x, t = threadIdx.x;
  __shared__ float zc[NN * NKF];
  __shared__ float Amat[NN][NN + 1];
  __shared__ float Li[NN][NN + 1];
  __shared__ float z2s[NN], ys[NN], al[NN];
  const float* zcg = z + (size_t)c * NN * NKF;
  for (int i = t; i < NN * NKF; i += 128) zc[i] = zcg[i];
  __syncthreads();
  if (t < NN) {
    float s = 0.f;
    for (int k = 0; k < NKF; ++k) { float v = zc[t * NKF + k]; s += v * v; }
    z2s[t] = s;
    z2g[c * NN + t] = s;
  }
  __syncthreads();
  float inv2 = 0.5f * expf(-2.0f * ll[0]);
  for (int e = t; e < NN * NN; e += 128) {
    int n = e / NN, m = e % NN;
    float d = 0.f;
    for (int k = 0; k < NKF; ++k) d += zc[n * NKF + k] * zc[m * NKF + k];
    float d2 = fmaxf(z2s[n] + z2s[m] - 2.0f * d, 0.0f);
    float v = expf(-d2 * inv2);
    if (n == m) v += 1e-4f;
    Amat[n][m] = v;
  }
  __syncthreads();
  // in-place Cholesky (lower) in Amat
  for (int j = 0; j < NN; ++j) {
    if (t == 0) {
      float s = Amat[j][j];
      for (int p = 0; p < j; ++p) s -= Amat[j][p] * Amat[j][p];
      Amat[j][j] = sqrtf(s);
    }
    __syncthreads();
    if (t > j && t < NN) {
      float s = Amat[t][j];
      for (int p = 0; p < j; ++p) s -= Amat[t][p] * Amat[j][p];
      Amat[t][j] = s / Amat[j][j];
    }
    __syncthreads();
  }
  // Linv column j per thread (no cross-thread deps)
  if (t < NN) {
    int j = t;
    for (int n = 0; n < NN; ++n) {
      float s;
      if (n < j) s = 0.f;
      else {
        s = (n == j) ? 1.f : 0.f;
        for (int m = j; m < n; ++m) s -= Amat[n][m] * Li[m][j];
        s /= Amat[n][n];
      }
      Li[n][j] = s;
    }
  }
  if (t == 0) {
    const float* mc = vm + c * NN;
    for (int n = 0; n < NN; ++n) {
      float s = mc[n];
      for (int m = 0; m < n; ++m) s -= Amat[n][m] * ys[m];
      ys[n] = s / Amat[n][n];
    }
    for (int n = NN - 1; n >= 0; --n) {
      float s = ys[n];
      for (int m = n + 1; m < NN; ++m) s -= Amat[m][n] * al[m];
      al[n] = s / Amat[n][n];
    }
  }
  __syncthreads();
  for (int e = t; e < NN * NN; e += 128)
    Lig[(size_t)c * NN * NN + e] = Li[e / NN][e % NN];
  if (t < NN) alphag[c * NN + t] = al[t];
  unsigned short* zp = zpad + (size_t)c * 32 * NKF;
  for (int i = t; i < 32 * NKF; i += 128) {
    int n = i >> 7;
    zp[i] = (n < NN) ? f2bf(zc[n * NKF + (i & 127)]) : (unsigned short)0;
  }
}

// ==================== GP main: MFMA k_xz + logits + var_c ====================
__global__ __launch_bounds__(256) void gp_main(const unsigned short* __restrict__ Hpb,
                                               const float* __restrict__ h2g,
                                               const unsigned short* __restrict__ zpad,
                                               const float* __restrict__ z2g,
                                               const float* __restrict__ Lig,
                                               const float* __restrict__ alphag,
                                               const float* __restrict__ ll,
                                               float* __restrict__ logitsT,
                                               float* __restrict__ varT) {
  int c = blockIdx.y, b0 = blockIdx.x * 256, t = threadIdx.x;
  int w = t >> 6, lane = t & 63;
  __shared__ __align__(16) unsigned short zs[32 * 136];
  __shared__ float kxs[256][21];
  __shared__ float Ls[NN][21];
  __shared__ float z2s[32], al[NN], ht2[256];

  {
    const unsigned short* zp = zpad + (size_t)c * 32 * NKF;
    int n = t >> 3, k = (t & 7) * 16;
    u16x8 a = *(const u16x8*)(zp + n * NKF + k);
    u16x8 b = *(const u16x8*)(zp + n * NKF + k + 8);
    *(u16x8*)&zs[n * 136 + k] = a;
    *(u16x8*)&zs[n * 136 + k + 8] = b;
  }
  for (int i = t; i < NN * NN; i += 256) Ls[i / NN][i % NN] = Lig[(size_t)c * NN * NN + i];
  if (t < 32) z2s[t] = (t < NN) ? z2g[c * NN + t] : 0.f;
  if (t < NN) al[t] = alphag[c * NN + t];
  ht2[t] = h2g[b0 + t];
  float inv2 = 0.5f * __expf(-2.0f * ll[0]);
  __syncthreads();

  f32x4 acc[4][2] = {};
  const unsigned short* hbase = Hpb + (size_t)(b0 + w * 64 + (lane & 15)) * NKF + (lane >> 4) * 8;
  #pragma unroll
  for (int ks = 0; ks < 4; ++ks) {
    s16x8 af[4], bfr[2];
    #pragma unroll
    for (int i = 0; i < 4; ++i) af[i] = *(const s16x8*)(hbase + (size_t)i * 16 * NKF + ks * 32);
    #pragma unroll
    for (int j = 0; j < 2; ++j)
      bfr[j] = *(const s16x8*)&zs[(j * 16 + (lane & 15)) * 136 + ks * 32 + (lane >> 4) * 8];
    #pragma unroll
    for (int i = 0; i < 4; ++i)
      #pragma unroll
      for (int j = 0; j < 2; ++j)
        acc[i][j] = __builtin_amdgcn_mfma_f32_16x16x32_bf16(af[i], bfr[j], acc[i][j], 0, 0, 0);
  }

  #pragma unroll
  for (int i = 0; i < 4; ++i)
    #pragma unroll
    for (int j = 0; j < 2; ++j) {
      int col = j * 16 + (lane & 15);
      #pragma unroll
      for (int r = 0; r < 4; ++r) {
        int rl = w * 64 + i * 16 + (lane >> 4) * 4 + r;
        float d2 = fmaxf(ht2[rl] + z2s[col] - 2.0f * acc[i][j][r], 0.0f);
        float kx = __expf(-d2 * inv2);
        if (col < NN) kxs[rl][col] = kx;
      }
    }
  __syncthreads();

  float kr[NN];
  #pragma unroll
  for (int n = 0; n < NN; ++n) kr[n] = kxs[t][n];
  float lg = 0.f;
  #pragma unroll
  for (int n = 0; n < NN; ++n) lg += kr[n] * al[n];
  logitsT[(size_t)c * NB + b0 + t] = lg;

  // vsum = ||Linv k||^2 — dependency-free dot products, no divides
  float vsum = 0.f;
  #pragma unroll
  for (int n = 0; n < NN; ++n) {
    float wv = 0.f;
    #pragma unroll
    for (int m = 0; m <= n; ++m) wv += Ls[n][m] * kr[m];
    vsum += wv * wv;
  }
  varT[(size_t)c * NB + b0 + t] = fmaxf(1.0f - vsum, 0.0f);
}

// ==================== transpose + softmax + uncertainty mean ====================
__global__ __launch_bounds__(256) void softmax_t(const float* __restrict__ logitsT,
                                                 const float* __restrict__ varT,
                                                 float* __restrict__ probs,
                                                 float* __restrict__ logits_out,
                                                 float* __restrict__ unc) {
  int b0 = blockIdx.x * 64, t = threadIdx.x;
  __shared__ float tile[NC][65];
  __shared__ float redmx[4][64], redsm[4][64], redvs[4][64], mxs[64], invs[64];
  for (int i = t; i < NC * 64; i += 256) {
    int cc = i >> 6, j = i & 63;
    tile[cc][j] = logitsT[(size_t)cc * NB + b0 + j];
  }
  __syncthreads();
  int j = t & 63, p = t >> 6;
  float mx = -1e30f, vs = 0.f;
  for (int cc = p * 50; cc < p * 50 + 50; ++cc) {
    mx = fmaxf(mx, tile[cc][j]);
    vs += varT[(size_t)cc * NB + b0 + j];
  }
  redmx[p][j] = mx;
  redvs[p][j] = vs;
  __syncthreads();
  if (p == 0) {
    mxs[j] = fmaxf(fmaxf(redmx[0][j], redmx[1][j]), fmaxf(redmx[2][j], redmx[3][j]));
    unc[b0 + j] = (redvs[0][j] + redvs[1][j] + redvs[2][j] + redvs[3][j]) * (1.0f / NC);
  }
  __syncthreads();
  float m2 = mxs[j], sm = 0.f;
  for (int cc = p * 50; cc < p * 50 + 50; ++cc) sm += __expf(tile[cc][j] - m2);
  redsm[p][j] = sm;
  __syncthreads();
  if (p == 0) invs[j] = 1.0f / (redsm[0][j] + redsm[1][j] + redsm[2][j] + redsm[3][j]);
  __syncthreads();
  for (int i = t; i < 64 * NC; i += 256) {
    int jj = i / NC, cc = i % NC;
    float lv = tile[cc][jj];
    size_t o = (size_t)(b0 + jj) * NC + cc;
    probs[o] = __expf(lv - mxs[jj]) * invs[jj];
    logits_out[o] = lv;
  }
}

// ==================== launch ====================
extern "C" void kernel_launch(void* const* d_in, const int* in_sizes, int n_in,
                              void* d_out, int out_size, void* d_ws, size_t ws_size,
                              hipStream_t stream) {
  if (ws_size < WS_NEED) return;

  const float* X   = (const float*)d_in[0];
  const float* g1  = (const float*)d_in[1];
  const float* be1 = (const float*)d_in[2];
  const float* W1  = (const float*)d_in[3];
  const float* b1  = (const float*)d_in[4];
  const float* g2  = (const float*)d_in[5];
  const float* be2 = (const float*)d_in[6];
  const float* W2  = (const float*)d_in[7];
  const float* b2  = (const float*)d_in[8];
  const float* Wp  = (const float*)d_in[9];
  const float* bp  = (const float*)d_in[10];
  const float* ll  = (const float*)d_in[11];
  const float* Z   = (const float*)d_in[12];
  const float* VM  = (const float*)d_in[13];

  char* ws = (char*)d_ws;
  unsigned short* W1bf = (unsigned short*)(ws + OFF_W1BF);
  unsigned short* W2bf = (unsigned short*)(ws + OFF_W2BF);
  unsigned short* Wpbf = (unsigned short*)(ws + OFF_WPBF);
  unsigned short* Xbf  = (unsigned short*)(ws + OFF_XBF);
  unsigned short* H2bf = (unsigned short*)(ws + OFF_H2BF);
  unsigned short* H1bf = (unsigned short*)(ws + OFF_H1BF);
  unsigned short* H1n  = (unsigned short*)(ws + OFF_H1N);
  float* Hp    = (float*)(ws + OFF_HP);
  float* h2s   = (float*)(ws + OFF_H2S);
  float* vb    = (float*)(ws + OFF_PV);
  float* slots = vb + 2 * 2 * 2048;
  float* sinv  = (float*)(ws + OFF_SINV);
  float* z2g   = (float*)(ws + OFF_Z2);
  float* Lg    = (float*)(ws + OFF_LC);
  float* alphag= (float*)(ws + OFF_AL);

  // gram-phase aliases
  unsigned short* W1T  = (unsigned short*)(ws + GOFF_W1T);
  unsigned short* Wp0  = (unsigned short*)(ws + GOFF_WP0);
  unsigned short* G1a  = (unsigned short*)(ws + GOFF_G1A);
  unsigned short* G1b  = (unsigned short*)(ws + GOFF_G1B);
  float*          Gpacc= (float*)(ws + GOFF_GPACC);
  unsigned short* W20  = (unsigned short*)(ws + GOFF_W20);
  unsigned short* G2c  = (unsigned short*)(ws + GOFF_G2C);
  unsigned short* G2d  = (unsigned short*)(ws + GOFF_G2D);
  // GP-phase aliases
  unsigned short* Hpb  = (unsigned short*)(ws + OFF_HPBF);
  unsigned short* zpad = (unsigned short*)(ws + OFF_ZPAD);
  float* logitsT = (float*)(ws + OFF_LGT);
  float* varT    = (float*)(ws + OFF_VART);

  float* out    = (float*)d_out;
  float* logits = out + (size_t)NB * NC;
  float* unc    = out + (size_t)2 * NB * NC;

  hipMemsetAsync(Hp, 0, (size_t)NB * NKF * 4, stream);
  hipMemsetAsync(Gpacc, 0, (size_t)NKF * NKF * 4, stream);

  // ---- spectral norms ----
  cast_bf<<<dim3(2048), 256, 0, stream>>>(W2, W20, NH * NH);
  cast_bf<<<dim3(128), 256, 0, stream>>>(Wp, Wp0, NKF * NH);
  transpose_cast<<<dim3(NE / 64, NH / 64), 256, 0, stream>>>(W1, W1T, NH, NE);
  gemm_nt<1><<<dim3(1, 1, 16), 256, 0, stream>>>(Wp0, Wp0, nullptr, (void*)Gpacc, NKF, NKF, NH, NH / 16, 1.0f);
  gp_power<<<dim3(1), 256, 0, stream>>>(Gpacc, sinv);
  gemm_nt<3><<<dim3(NE / 128, NE / 128), 256, 0, stream>>>(W1T, W1T, nullptr, (void*)G1a, NE, NE, NH, 0, 1.0f);
  gemm_nt<3><<<dim3(NH / 128, NH / 128), 256, 0, stream>>>(W20, W20, nullptr, (void*)G2c, NH, NH, NH, 0, 1.0f);
  gemm_nt<3><<<dim3(NE / 128, NE / 128), 256, 0, stream>>>(G1a, G1a, nullptr, (void*)G1b, NE, NE, NE, 0, 1.0f);
  gemm_nt<3><<<dim3(NH / 128, NH / 128), 256, 0, stream>>>(G2c, G2c, nullptr, (void*)G2d, NH, NH, NH, 0, 1.0f);
  gemm_nt<3><<<dim3(NE / 128, NE / 128), 256, 0, stream>>>(G1b, G1b, nullptr, (void*)G1a, NE, NE, NE, 0, 0.0625f);
  gemm_nt<3><<<dim3(NH / 128, NH / 128), 256, 0, stream>>>(G2d, G2d, nullptr, (void*)G2c, NH, NH, NH, 0, 0.0625f);
  init_gram<<<dim3(1), 256, 0, stream>>>(vb, slots);
  for (int i = 0; i < NITER_R; ++i)
    gram_iter<<<dim3(352), 256, 0, stream>>>(G1a, G2c, vb, slots, i);
  finalize_sigma<<<dim3(1), 64, 0, stream>>>(slots, sinv);
  scale_weights<<<dim3(2944), 256, 0, stream>>>(W1, W2, Wp, sinv, W1bf, W2bf, Wpbf);

  // ---- MLP ----
  ln_e<<<dim3(NB / 4), 256, 0, stream>>>(X, g1, be1, Xbf);
  gemm_nt<0><<<dim3(NB / 128, NH / 128), 256, 0, stream>>>(Xbf, W1bf, b1, (void*)H1bf, NB, NH, NE, 0, 1.0f);
  ln_h<<<dim3(NB / 4), 256, 0, stream>>>(H1bf, g2, be2, H1n);
  gemm_nt<0><<<dim3(NB / 128, NH / 128), 256, 0, stream>>>(H1n, W2bf, b2, (void*)H2bf, NB, NH, NH, 0, 1.0f);
  gemm_nt<1><<<dim3(NB / 128, 1, 8), 256, 0, stream>>>(H2bf, Wpbf, bp, (void*)Hp, NB, NKF, NH, NH / 8, 1.0f);
  finish_proj<<<dim3(NB / 4), 256, 0, stream>>>(Hp, bp, Hpb, h2s);

  // ---- GP head ----
  gp_prep<<<dim3(NC), 128, 0, stream>>>(Z, VM, ll, z2g, Lg, alphag, zpad);
  gp_main<<<dim3(NB / 256, NC), 256, 0, stream>>>(Hpb, h2s, zpad, z2g, Lg, alphag, ll, logitsT, varT);
  softmax_t<<<dim3(NB / 64), 256, 0, stream>>>(logitsT, varT, out, logits, unc);
}

// Round 6
// 602.441 us; speedup vs baseline: 1.2038x; 1.0125x over previous
//
#include <hip/hip_runtime.h>
#include <cstdint>
#include <cstddef>

// ---------------- problem dims ----------------
#define NB 4096   // batch
#define NE 768    // in features
#define NH 2048   // hidden
#define NKF 128   // GP feature dim
#define NC 200    // classes
#define NN 20     // inducing points per class
#define NITER_R 10  // iterations on G^4 (== 40 on G)

typedef __attribute__((ext_vector_type(8))) short s16x8;
typedef __attribute__((ext_vector_type(8))) unsigned short u16x8;
typedef __attribute__((ext_vector_type(4))) unsigned short u16x4;
typedef __attribute__((ext_vector_type(4))) float f32x4;

__device__ inline unsigned short f2bf(float x) {
  unsigned u = __builtin_bit_cast(unsigned, x);
  u += 0x7fffu + ((u >> 16) & 1u);
  return (unsigned short)(u >> 16);
}
__device__ inline float bf2f(unsigned short h) {
  return __builtin_bit_cast(float, (unsigned)h << 16);
}
__device__ inline float gelu_exact(float x) {
  return x * 0.5f * (1.0f + erff(x * 0.70710678118654752f));
}

// async global->LDS 16B/lane. lds base must be wave-uniform; HW writes base+lane*16.
__device__ inline void gl16(const unsigned short* g, unsigned short* l) {
  __builtin_amdgcn_global_load_lds(
      (const __attribute__((address_space(1))) unsigned int*)(uintptr_t)(g),
      (__attribute__((address_space(3))) unsigned int*)(uintptr_t)(l),
      16, 0, 0);
}

// ---------------- workspace layout (bytes) ----------------
constexpr size_t SZ_W1BF = (size_t)NH * NE * 2;
constexpr size_t SZ_W2BF = (size_t)NH * NH * 2;
constexpr size_t SZ_WPBF = (size_t)NKF * NH * 2;
constexpr size_t SZ_SLOT = (size_t)NB * NH * 2;  // 16.8 MB

constexpr size_t OFF_W1BF = 0;
constexpr size_t OFF_W2BF = OFF_W1BF + SZ_W1BF;
constexpr size_t OFF_WPBF = OFF_W2BF + SZ_W2BF;
constexpr size_t OFF_XBF  = OFF_WPBF + SZ_WPBF;  // slot A
constexpr size_t OFF_H2BF = OFF_XBF;             // gemm2 out (after gemm1 consumed Xbf)
constexpr size_t OFF_H1BF = OFF_XBF + SZ_SLOT;   // slot B
constexpr size_t OFF_H1N  = OFF_H1BF + SZ_SLOT;  // slot C
constexpr size_t OFF_HP   = OFF_H1N + SZ_SLOT;   // projection fp32 [NB][NKF]
constexpr size_t OFF_H2S  = OFF_HP + (size_t)NB * NKF * 4;  // |h|^2 per row
constexpr size_t OFF_PV   = OFF_H2S + (size_t)NB * 4;       // iter vectors + norm slots
constexpr size_t OFF_SINV = OFF_PV + (size_t)3 * 3 * 2048 * 4;
constexpr size_t OFF_Z2   = OFF_SINV + 256;
constexpr size_t OFF_LC   = OFF_Z2 + (size_t)NC * NN * 4;
constexpr size_t OFF_AL   = OFF_LC + (size_t)NC * NN * NN * 4;
constexpr size_t WS_NEED  = OFF_AL + (size_t)NC * NN * 4;

// --- gram-phase aliases (dead before the MLP writes these slots) ---
constexpr size_t GOFF_W1T   = OFF_XBF;                            // bf16 [768][2048]
constexpr size_t GOFF_WP0   = GOFF_W1T + (size_t)NE * NH * 2;     // bf16 [128][2048]
constexpr size_t GOFF_G1A   = GOFF_WP0 + (size_t)NKF * NH * 2;    // bf16 768^2
constexpr size_t GOFF_G1B   = GOFF_G1A + (size_t)NE * NE * 2;     // bf16 768^2
constexpr size_t GOFF_GPACC = GOFF_G1B + (size_t)NE * NE * 2;     // f32 128^2
static_assert(GOFF_GPACC + (size_t)NKF * NKF * 4 <= OFF_XBF + SZ_SLOT, "slotA overflow");
constexpr size_t GOFF_W20 = OFF_H1BF;                             // bf16 2048^2
constexpr size_t GOFF_G2C = OFF_H1N;                              // bf16 2048^2
constexpr size_t GOFF_G2D = OFF_H1N + (size_t)NH * NH * 2;        // bf16 2048^2
// --- GP-phase aliases ---
constexpr size_t OFF_HPBF = OFF_H1BF;                          // bf16 [4096][128]
constexpr size_t OFF_ZPAD = OFF_H1BF + (size_t)NB * NKF * 2;   // bf16 [200][32][128]
constexpr size_t OFF_LGT  = OFF_H1N;                           // f32 [200][4096] logitsT
constexpr size_t OFF_VART = OFF_LGT + (size_t)NC * NB * 4;     // f32 [200][4096] var_c
static_assert(OFF_VART + (size_t)NC * NB * 4 <= OFF_H1N + SZ_SLOT, "slotC overflow");

// ==================== helpers ====================
__global__ __launch_bounds__(256) void cast_bf(const float* __restrict__ in,
                                               unsigned short* __restrict__ out, int n) {
  for (int i = blockIdx.x * 256 + threadIdx.x; i < n; i += gridDim.x * 256)
    out[i] = f2bf(in[i]);
}

// transpose+cast: fp32 [R][C] -> bf16 [C][R]
__global__ __launch_bounds__(256) void transpose_cast(const float* __restrict__ in,
                                                      unsigned short* __restrict__ out,
                                                      int R, int C) {
  __shared__ float tile[64][65];
  int c0 = blockIdx.x * 64, r0 = blockIdx.y * 64;
  int tx = threadIdx.x & 63, ty = threadIdx.x >> 6;
  #pragma unroll
  for (int j = 0; j < 16; ++j) {
    int r = ty + j * 4;
    tile[r][tx] = in[(size_t)(r0 + r) * C + c0 + tx];
  }
  __syncthreads();
  #pragma unroll
  for (int j = 0; j < 16; ++j) {
    int cc = ty + j * 4;
    out[(size_t)(c0 + cc) * R + r0 + tx] = f2bf(tile[tx][cc]);
  }
}

// ==================== unnormalized power iteration on G^4/16 (bf16) ====================
__global__ __launch_bounds__(256) void init_gram(float* __restrict__ vb,
                                                 float* __restrict__ slots) {
  int t = threadIdx.x;
  for (int i = t; i < 2 * 2 * 2048; i += 256) vb[i] = 0.0f;
  for (int i = t; i < 32; i += 256) slots[i] = 0.0f;
  __syncthreads();
  const int kd[2] = {NE, NH};
  for (int m = 0; m < 2; ++m)
    for (int k = t; k < kd[m]; k += 256) vb[(m * 2) * 2048 + k] = 1.0f;
}

__global__ __launch_bounds__(256) void gram_iter(const unsigned short* __restrict__ G1q,
                                                 const unsigned short* __restrict__ G2q,
                                                 float* __restrict__ vb,
                                                 float* __restrict__ slots, int iter) {
  int b = blockIdx.x, t = threadIdx.x;
  int m, r0, Kd;
  const unsigned short* G;
  if (b < 96) { m = 0; G = G1q; Kd = NE; r0 = b * 8; }
  else        { m = 1; G = G2q; Kd = NH; r0 = (b - 96) * 8; }

  const float* vin = vb + ((size_t)m * 2 + (iter & 1)) * 2048;
  float* vout      = vb + ((size_t)m * 2 + ((iter + 1) & 1)) * 2048;

  __shared__ float vs[2048];
  for (int k = t; k < Kd; k += 256) vs[k] = vin[k];
  __syncthreads();

  int w = t >> 6, lane = t & 63;
  float nrm = 0.f;
  #pragma unroll
  for (int rr = 0; rr < 2; ++rr) {
    int row = r0 + w * 2 + rr;
    const unsigned short* gr = G + (size_t)row * Kd;
    float s = 0.f;
    for (int k0 = lane * 8; k0 < Kd; k0 += 512) {
      u16x8 u = *(const u16x8*)(gr + k0);
      #pragma unroll
      for (int q = 0; q < 8; ++q) s += bf2f(u[q]) * vs[k0 + q];
    }
    for (int off = 32; off; off >>= 1) s += __shfl_down(s, off);
    if (lane == 0) { vout[row] = s; nrm += s * s; }
  }
  if (lane == 0) atomicAdd(&slots[m * 16 + iter + 1], nrm);
}

__global__ void finalize_sigma(const float* __restrict__ slots, float* __restrict__ sinv) {
  int m = threadIdx.x;
  if (m < 2) {
    float lam4 = 16.0f * sqrtf(slots[m * 16 + NITER_R] / slots[m * 16 + NITER_R - 1]);
    sinv[m] = powf(lam4, -0.125f);
  }
}

// power iteration on Gp (128x128 f32): G-block in REGISTERS per thread, conflict-free.
__global__ __launch_bounds__(256) void gp_power(const float* __restrict__ Gp,
                                                float* __restrict__ sinv) {
  __shared__ float v[NKF];
  __shared__ float pred[8][NKF];
  __shared__ float nacc[2];
  int t = threadIdx.x;
  int rg = (t & 31) * 4;
  int ks = t >> 5;
  f32x4 Greg[16];
  #pragma unroll
  for (int kk = 0; kk < 16; ++kk)
    Greg[kk] = *(const f32x4*)(Gp + (size_t)(ks * 16 + kk) * NKF + rg);
  if (t < NKF) v[t] = 1.0f;
  __syncthreads();
  float s_last0 = 1.f, s_last1 = 1.f;
  for (int it = 0; it < 40; ++it) {
    f32x4 p = {0.f, 0.f, 0.f, 0.f};
    #pragma unroll
    for (int kq = 0; kq < 4; ++kq) {
      f32x4 vv = *(const f32x4*)&v[ks * 16 + kq * 4];
      p += Greg[kq * 4 + 0] * vv[0];
      p += Greg[kq * 4 + 1] * vv[1];
      p += Greg[kq * 4 + 2] * vv[2];
      p += Greg[kq * 4 + 3] * vv[3];
    }
    *(f32x4*)&pred[ks][rg] = p;
    __syncthreads();
    float s = 0.f;
    if (t < NKF) {
      #pragma unroll
      for (int q = 0; q < 8; ++q) s += pred[q][t];
      v[t] = s;
    }
    if (it >= 38) {
      float q2 = (t < NKF) ? s * s : 0.f;
      #pragma unroll
      for (int off = 32; off; off >>= 1) q2 += __shfl_down(q2, off);
      if (t == 0) nacc[0] = q2;
      if (t == 64) nacc[1] = q2;
    }
    __syncthreads();
    if (it == 38 && t == 0) s_last0 = nacc[0] + nacc[1];
    if (it == 39 && t == 0) s_last1 = nacc[0] + nacc[1];
  }
  if (t == 0) sinv[2] = powf(s_last1 / s_last0, -0.25f);
}

__global__ __launch_bounds__(256) void scale_weights(const float* __restrict__ W1,
                                                     const float* __restrict__ W2,
                                                     const float* __restrict__ Wp,
                                                     const float* __restrict__ sinv,
                                                     unsigned short* __restrict__ W1bf,
                                                     unsigned short* __restrict__ W2bf,
                                                     unsigned short* __restrict__ Wpbf) {
  const int n1 = NH * NE, n2 = NH * NH;
  float s0 = sinv[0], s1 = sinv[1], s2 = sinv[2];
  int base = blockIdx.x * 2048;
  for (int i = threadIdx.x; i < 2048; i += 256) {
    int g = base + i;
    if (g < n1) {
      W1bf[g] = f2bf(W1[g] * s0);
    } else if (g < n1 + n2) {
      int q = g - n1; W2bf[q] = f2bf(W2[q] * s1);
    } else {
      int q = g - n1 - n2; Wpbf[q] = f2bf(Wp[q] * s2);
    }
  }
}

// ==================== layernorms ====================
__global__ __launch_bounds__(256) void ln_e(const float* __restrict__ X,
                                            const float* __restrict__ g,
                                            const float* __restrict__ b,
                                            unsigned short* __restrict__ out) {
  int wid = threadIdx.x >> 6, lane = threadIdx.x & 63;
  int row = blockIdx.x * 4 + wid;
  const float* xr = X + (size_t)row * NE;
  float4 v[3];
  float s = 0.f, sq = 0.f;
  #pragma unroll
  for (int j = 0; j < 3; ++j) {
    v[j] = *(const float4*)(xr + j * 256 + lane * 4);
    s += v[j].x + v[j].y + v[j].z + v[j].w;
    sq += v[j].x * v[j].x + v[j].y * v[j].y + v[j].z * v[j].z + v[j].w * v[j].w;
  }
  for (int off = 32; off; off >>= 1) { s += __shfl_down(s, off); sq += __shfl_down(sq, off); }
  s = __shfl(s, 0); sq = __shfl(sq, 0);
  float mean = s * (1.0f / NE);
  float var = sq * (1.0f / NE) - mean * mean;
  float rstd = rsqrtf(var + 1e-5f);
  unsigned short* orow = out + (size_t)row * NE;
  #pragma unroll
  for (int j = 0; j < 3; ++j) {
    int e0 = j * 256 + lane * 4;
    float4 gg = *(const float4*)(g + e0);
    float4 bb = *(const float4*)(b + e0);
    u16x4 o;
    o[0] = f2bf((v[j].x - mean) * rstd * gg.x + bb.x);
    o[1] = f2bf((v[j].y - mean) * rstd * gg.y + bb.y);
    o[2] = f2bf((v[j].z - mean) * rstd * gg.z + bb.z);
    o[3] = f2bf((v[j].w - mean) * rstd * gg.w + bb.w);
    *(u16x4*)(orow + e0) = o;
  }
}

__global__ __launch_bounds__(256) void ln_h(const unsigned short* __restrict__ X,
                                            const float* __restrict__ g,
                                            const float* __restrict__ b,
                                            unsigned short* __restrict__ out) {
  int wid = threadIdx.x >> 6, lane = threadIdx.x & 63;
  int row = blockIdx.x * 4 + wid;
  const unsigned short* xr = X + (size_t)row * NH;
  float xv[32];
  float s = 0.f, sq = 0.f;
  #pragma unroll
  for (int j = 0; j < 4; ++j) {
    u16x8 u = *(const u16x8*)(xr + j * 512 + lane * 8);
    #pragma unroll
    for (int q = 0; q < 8; ++q) {
      float x = bf2f(u[q]);
      xv[j * 8 + q] = x; s += x; sq += x * x;
    }
  }
  for (int off = 32; off; off >>= 1) { s += __shfl_down(s, off); sq += __shfl_down(sq, off); }
  s = __shfl(s, 0); sq = __shfl(sq, 0);
  float mean = s * (1.0f / NH);
  float var = sq * (1.0f / NH) - mean * mean;
  float rstd = rsqrtf(var + 1e-5f);
  unsigned short* orow = out + (size_t)row * NH;
  #pragma unroll
  for (int j = 0; j < 4; ++j) {
    int e0 = j * 512 + lane * 8;
    float4 ga = *(const float4*)(g + e0);
    float4 gb = *(const float4*)(g + e0 + 4);
    float4 ba = *(const float4*)(b + e0);
    float4 bb = *(const float4*)(b + e0 + 4);
    u16x8 o;
    o[0] = f2bf((xv[j*8+0] - mean) * rstd * ga.x + ba.x);
    o[1] = f2bf((xv[j*8+1] - mean) * rstd * ga.y + ba.y);
    o[2] = f2bf((xv[j*8+2] - mean) * rstd * ga.z + ba.z);
    o[3] = f2bf((xv[j*8+3] - mean) * rstd * ga.w + ba.w);
    o[4] = f2bf((xv[j*8+4] - mean) * rstd * gb.x + bb.x);
    o[5] = f2bf((xv[j*8+5] - mean) * rstd * gb.y + bb.y);
    o[6] = f2bf((xv[j*8+6] - mean) * rstd * gb.z + bb.z);
    o[7] = f2bf((xv[j*8+7] - mean) * rstd * gb.w + bb.w);
    *(u16x8*)(orow + e0) = o;
  }
}

// ==================== bf16 MFMA GEMM (NT), 2-phase dbuf + T2 XOR swizzle ====================
// LDS [2][128][32] linear (global_load_lds). Both-sides swizzle (rule #21):
//  - staging: thread t loads global chunk (t&3)^((t>>3)&3) of its row -> LDS stays linear
//  - read: fragment k-chunk (lane>>4)^((row>>1)&3) recovers global chunk lane>>4
// Effect: each 32-lane LDS phase hits all 32 banks at 4 dwords/bank (was 16 banks @ 8).
template <int EPI>
__global__ __launch_bounds__(256) void gemm_nt(const unsigned short* __restrict__ A,
                                               const unsigned short* __restrict__ Bm,
                                               const float* __restrict__ bias,
                                               void* __restrict__ Cout,
                                               int M, int Nn, int Kk, int KCH,
                                               float cscale) {
  __shared__ __align__(16) unsigned short As[2][128 * 32];
  __shared__ __align__(16) unsigned short Bs[2][128 * 32];
  int t = threadIdx.x;
  int bm0 = blockIdx.x * 128, bn0 = blockIdx.y * 128;
  int wid = t >> 6, lane = t & 63;
  int wm = wid >> 1, wn = wid & 1;

  int kb = 0, ke = Kk;
  if (KCH > 0) { kb = blockIdx.z * KCH; ke = kb + KCH; }

  f32x4 acc[4][4] = {};

  int lrow = t >> 2;                               // staged row (and row+64)
  int lk8 = (((t & 3) ^ ((t >> 3) & 3)) * 8);      // swizzled source k-chunk
  const unsigned short* Ag = A + (size_t)(bm0 + lrow) * Kk + lk8;
  const unsigned short* Bg = Bm + (size_t)(bn0 + lrow) * Kk + lk8;

  int arow = wm * 64 + (lane & 15);
  int brow = wn * 64 + (lane & 15);
  int kca = (((lane >> 4) ^ ((arow >> 1) & 3)) * 8);  // swizzled read chunk (A)
  int kcb = (((lane >> 4) ^ ((brow >> 1) & 3)) * 8);  // swizzled read chunk (B)

  #define STAGE(nb, koff)                                   \
    do {                                                    \
      gl16(Ag + (koff), &As[nb][wid * 512]);                \
      gl16(Ag + (size_t)64 * Kk + (koff), &As[nb][2048 + wid * 512]); \
      gl16(Bg + (koff), &Bs[nb][wid * 512]);                \
      gl16(Bg + (size_t)64 * Kk + (koff), &Bs[nb][2048 + wid * 512]); \
    } while (0)

  STAGE(0, kb);
  __syncthreads();
  int cb = 0;
  for (int ks = kb; ks < ke; ks += 32) {
    if (ks + 32 < ke) STAGE(cb ^ 1, ks + 32);
    s16x8 af[4], bfr[4];
    #pragma unroll
    for (int i = 0; i < 4; ++i) af[i] = *(const s16x8*)&As[cb][(arow + i * 16) * 32 + kca];
    #pragma unroll
    for (int j = 0; j < 4; ++j) bfr[j] = *(const s16x8*)&Bs[cb][(brow + j * 16) * 32 + kcb];
    #pragma unroll
    for (int i = 0; i < 4; ++i)
      #pragma unroll
      for (int j = 0; j < 4; ++j)
        acc[i][j] = __builtin_amdgcn_mfma_f32_16x16x32_bf16(af[i], bfr[j], acc[i][j], 0, 0, 0);
    __syncthreads();   // drains this iter's STAGE loads + protects buffer swap
    cb ^= 1;
  }
  #undef STAGE

  // D layout: row = (lane>>4)*4 + reg, col = lane&15
  int crow0 = bm0 + wm * 64 + (lane >> 4) * 4;
  int ccol0 = bn0 + wn * 64 + (lane & 15);
  if constexpr (EPI == 0) {
    unsigned short* C = (unsigned short*)Cout;
    #pragma unroll
    for (int i = 0; i < 4; ++i) {
      #pragma unroll
      for (int j = 0; j < 4; ++j) {
        int col = ccol0 + j * 16;
        float bb = bias[col];
        #pragma unroll
        for (int r = 0; r < 4; ++r) {
          int row = crow0 + i * 16 + r;
          float x = acc[i][j][r] + bb;
          C[(size_t)row * Nn + col] = f2bf(gelu_exact(x));
        }
      }
    }
  } else if constexpr (EPI == 1) {
    float* C = (float*)Cout;
    #pragma unroll
    for (int i = 0; i < 4; ++i)
      #pragma unroll
      for (int j = 0; j < 4; ++j) {
        int col = ccol0 + j * 16;
        #pragma unroll
        for (int r = 0; r < 4; ++r) {
          int row = crow0 + i * 16 + r;
          atomicAdd(&C[(size_t)row * Nn + col], acc[i][j][r]);
        }
      }
  } else {
    unsigned short* C = (unsigned short*)Cout;
    #pragma unroll
    for (int i = 0; i < 4; ++i)
      #pragma unroll
      for (int j = 0; j < 4; ++j) {
        int col = ccol0 + j * 16;
        #pragma unroll
        for (int r = 0; r < 4; ++r) {
          int row = crow0 + i * 16 + r;
          C[(size_t)row * Nn + col] = f2bf(acc[i][j][r] * cscale);
        }
      }
  }
}

// add bias, |h|^2 per row, write bf16 h. one wave per row.
__global__ __launch_bounds__(256) void finish_proj(const float* __restrict__ Hp,
                                                   const float* __restrict__ bp,
                                                   unsigned short* __restrict__ Hpb,
                                                   float* __restrict__ h2) {
  int wid = threadIdx.x >> 6, lane = threadIdx.x & 63;
  int row = blockIdx.x * 4 + wid;
  const float* r = Hp + (size_t)row * NKF;
  float x0 = r[lane] + bp[lane];
  float x1 = r[lane + 64] + bp[lane + 64];
  float s = x0 * x0 + x1 * x1;
  for (int off = 32; off; off >>= 1) s += __shfl_down(s, off);
  unsigned short* hb = Hpb + (size_t)row * NKF;
  hb[lane] = f2bf(x0);
  hb[lane + 64] = f2bf(x1);
  if (lane == 0) h2[row] = s;
}

// ==================== GP prep: z2, k_zz Cholesky, alpha, L^-1, z bf16 padded ====================
__global__ __launch_bounds__(128) void gp_prep(const float* __restrict__ z,
                                               const float* __restrict__ vm,
                                               const float* __restrict__ ll,
                                               float* __restrict__ z2g,
                                               float* __restrict__ Lig,
                                               float* __restrict__ alphag,
                                               unsigned short* __restrict__ zpad) {
  int c = blockIdx.x, t = threadIdx.x;
  __shared__ float zc[NN * NKF];
  __shared__ float Amat[NN][NN + 1];
  __shared__ float Li[NN][NN + 1];
  __shared__ float z2s[NN], ys[NN], al[NN];
  const float* zcg = z + (size_t)c * NN * NKF;
  for (int i = t; i < NN * NKF; i += 128) zc[i] = zcg[i];
  __syncthreads();
  if (t < NN) {
    float s = 0.f;
    for (int k = 0; k < NKF; ++k) { float v = zc[t * NKF + k]; s += v * v; }
    z2s[t] = s;
    z2g[c * NN + t] = s;
  }
  __syncthreads();
  float inv2 = 0.5f * expf(-2.0f * ll[0]);
  for (int e = t; e < NN * NN; e += 128) {
    int n = e / NN, m = e % NN;
    float d = 0.f;
    for (int k = 0; k < NKF; ++k) d += zc[n * NKF + k] * zc[m * NKF + k];
    float d2 = fmaxf(z2s[n] + z2s[m] - 2.0f * d, 0.0f);
    float v = expf(-d2 * inv2);
    if (n == m) v += 1e-4f;
    Amat[n][m] = v;
  }
  __syncthreads();
  for (int j = 0; j < NN; ++j) {
    if (t == 0) {
      float s = Amat[j][j];
      for (int p = 0; p < j; ++p) s -= Amat[j][p] * Amat[j][p];
      Amat[j][j] = sqrtf(s);
    }
    __syncthreads();
    if (t > j && t < NN) {
      float s = Amat[t][j];
      for (int p = 0; p < j; ++p) s -= Amat[t][p] * Amat[j][p];
      Amat[t][j] = s / Amat[j][j];
    }
    __syncthreads();
  }
  if (t < NN) {
    int j = t;
    for (int n = 0; n < NN; ++n) {
      float s;
      if (n < j) s = 0.f;
      else {
        s = (n == j) ? 1.f : 0.f;
        for (int m = j; m < n; ++m) s -= Amat[n][m] * Li[m][j];
        s /= Amat[n][n];
      }
      Li[n][j] = s;
    }
  }
  if (t == 0) {
    const float* mc = vm + c * NN;
    for (int n = 0; n < NN; ++n) {
      float s = mc[n];
      for (int m = 0; m < n; ++m) s -= Amat[n][m] * ys[m];
      ys[n] = s / Amat[n][n];
    }
    for (int n = NN - 1; n >= 0; --n) {
      float s = ys[n];
      for (int m = n + 1; m < NN; ++m) s -= Amat[m][n] * al[m];
      al[n] = s / Amat[n][n];
    }
  }
  __syncthreads();
  for (int e = t; e < NN * NN; e += 128)
    Lig[(size_t)c * NN * NN + e] = Li[e / NN][e % NN];
  if (t < NN) alphag[c * NN + t] = al[t];
  unsigned short* zp = zpad + (size_t)c * 32 * NKF;
  for (int i = t; i < 32 * NKF; i += 128) {
    int n = i >> 7;
    zp[i] = (n < NN) ? f2bf(zc[n * NKF + (i & 127)]) : (unsigned short)0;
  }
}

// ==================== GP main: MFMA k_xz + logits + var_c ====================
__global__ __launch_bounds__(256) void gp_main(const unsigned short* __restrict__ Hpb,
                                               const float* __restrict__ h2g,
                                               const unsigned short* __restrict__ zpad,
                                               const float* __restrict__ z2g,
                                               const float* __restrict__ Lig,
                                               const float* __restrict__ alphag,
                                               const float* __restrict__ ll,
                                               float* __restrict__ logitsT,
                                               float* __restrict__ varT) {
  int c = blockIdx.y, b0 = blockIdx.x * 256, t = threadIdx.x;
  int w = t >> 6, lane = t & 63;
  __shared__ __align__(16) unsigned short zs[32 * 136];
  __shared__ float kxs[256][21];
  __shared__ float Ls[NN][21];
  __shared__ float z2s[32], al[NN], ht2[256];

  {
    const unsigned short* zp = zpad + (size_t)c * 32 * NKF;
    int n = t >> 3, k = (t & 7) * 16;
    u16x8 a = *(const u16x8*)(zp + n * NKF + k);
    u16x8 b = *(const u16x8*)(zp + n * NKF + k + 8);
    *(u16x8*)&zs[n * 136 + k] = a;
    *(u16x8*)&zs[n * 136 + k + 8] = b;
  }
  for (int i = t; i < NN * NN; i += 256) Ls[i / NN][i % NN] = Lig[(size_t)c * NN * NN + i];
  if (t < 32) z2s[t] = (t < NN) ? z2g[c * NN + t] : 0.f;
  if (t < NN) al[t] = alphag[c * NN + t];
  ht2[t] = h2g[b0 + t];
  float inv2 = 0.5f * __expf(-2.0f * ll[0]);
  __syncthreads();

  f32x4 acc[4][2] = {};
  const unsigned short* hbase = Hpb + (size_t)(b0 + w * 64 + (lane & 15)) * NKF + (lane >> 4) * 8;
  #pragma unroll
  for (int ks = 0; ks < 4; ++ks) {
    s16x8 af[4], bfr[2];
    #pragma unroll
    for (int i = 0; i < 4; ++i) af[i] = *(const s16x8*)(hbase + (size_t)i * 16 * NKF + ks * 32);
    #pragma unroll
    for (int j = 0; j < 2; ++j)
      bfr[j] = *(const s16x8*)&zs[(j * 16 + (lane & 15)) * 136 + ks * 32 + (lane >> 4) * 8];
    #pragma unroll
    for (int i = 0; i < 4; ++i)
      #pragma unroll
      for (int j = 0; j < 2; ++j)
        acc[i][j] = __builtin_amdgcn_mfma_f32_16x16x32_bf16(af[i], bfr[j], acc[i][j], 0, 0, 0);
  }

  #pragma unroll
  for (int i = 0; i < 4; ++i)
    #pragma unroll
    for (int j = 0; j < 2; ++j) {
      int col = j * 16 + (lane & 15);
      #pragma unroll
      for (int r = 0; r < 4; ++r) {
        int rl = w * 64 + i * 16 + (lane >> 4) * 4 + r;
        float d2 = fmaxf(ht2[rl] + z2s[col] - 2.0f * acc[i][j][r], 0.0f);
        float kx = __expf(-d2 * inv2);
        if (col < NN) kxs[rl][col] = kx;
      }
    }
  __syncthreads();

  float kr[NN];
  #pragma unroll
  for (int n = 0; n < NN; ++n) kr[n] = kxs[t][n];
  float lg = 0.f;
  #pragma unroll
  for (int n = 0; n < NN; ++n) lg += kr[n] * al[n];
  logitsT[(size_t)c * NB + b0 + t] = lg;

  float vsum = 0.f;
  #pragma unroll
  for (int n = 0; n < NN; ++n) {
    float wv = 0.f;
    #pragma unroll
    for (int m = 0; m <= n; ++m) wv += Ls[n][m] * kr[m];
    vsum += wv * wv;
  }
  varT[(size_t)c * NB + b0 + t] = fmaxf(1.0f - vsum, 0.0f);
}

// ==================== transpose + softmax + uncertainty mean ====================
__global__ __launch_bounds__(256) void softmax_t(const float* __restrict__ logitsT,
                                                 const float* __restrict__ varT,
                                                 float* __restrict__ probs,
                                                 float* __restrict__ logits_out,
                                                 float* __restrict__ unc) {
  int b0 = blockIdx.x * 64, t = threadIdx.x;
  __shared__ float tile[NC][65];
  __shared__ float redmx[4][64], redsm[4][64], redvs[4][64], mxs[64], invs[64];
  for (int i = t; i < NC * 64; i += 256) {
    int cc = i >> 6, j = i & 63;
    tile[cc][j] = logitsT[(size_t)cc * NB + b0 + j];
  }
  __syncthreads();
  int j = t & 63, p = t >> 6;
  float mx = -1e30f, vs = 0.f;
  for (int cc = p * 50; cc < p * 50 + 50; ++cc) {
    mx = fmaxf(mx, tile[cc][j]);
    vs += varT[(size_t)cc * NB + b0 + j];
  }
  redmx[p][j] = mx;
  redvs[p][j] = vs;
  __syncthreads();
  if (p == 0) {
    mxs[j] = fmaxf(fmaxf(redmx[0][j], redmx[1][j]), fmaxf(redmx[2][j], redmx[3][j]));
    unc[b0 + j] = (redvs[0][j] + redvs[1][j] + redvs[2][j] + redvs[3][j]) * (1.0f / NC);
  }
  __syncthreads();
  float m2 = mxs[j], sm = 0.f;
  for (int cc = p * 50; cc < p * 50 + 50; ++cc) sm += __expf(tile[cc][j] - m2);
  redsm[p][j] = sm;
  __syncthreads();
  if (p == 0) invs[j] = 1.0f / (redsm[0][j] + redsm[1][j] + redsm[2][j] + redsm[3][j]);
  __syncthreads();
  for (int i = t; i < 64 * NC; i += 256) {
    int jj = i / NC, cc = i % NC;
    float lv = tile[cc][jj];
    size_t o = (size_t)(b0 + jj) * NC + cc;
    probs[o] = __expf(lv - mxs[jj]) * invs[jj];
    logits_out[o] = lv;
  }
}

// ==================== launch ====================
extern "C" void kernel_launch(void* const* d_in, const int* in_sizes, int n_in,
                              void* d_out, int out_size, void* d_ws, size_t ws_size,
                              hipStream_t stream) {
  if (ws_size < WS_NEED) return;

  const float* X   = (const float*)d_in[0];
  const float* g1  = (const float*)d_in[1];
  const float* be1 = (const float*)d_in[2];
  const float* W1  = (const float*)d_in[3];
  const float* b1  = (const float*)d_in[4];
  const float* g2  = (const float*)d_in[5];
  const float* be2 = (const float*)d_in[6];
  const float* W2  = (const float*)d_in[7];
  const float* b2  = (const float*)d_in[8];
  const float* Wp  = (const float*)d_in[9];
  const float* bp  = (const float*)d_in[10];
  const float* ll  = (const float*)d_in[11];
  const float* Z   = (const float*)d_in[12];
  const float* VM  = (const float*)d_in[13];

  char* ws = (char*)d_ws;
  unsigned short* W1bf = (unsigned short*)(ws + OFF_W1BF);
  unsigned short* W2bf = (unsigned short*)(ws + OFF_W2BF);
  unsigned short* Wpbf = (unsigned short*)(ws + OFF_WPBF);
  unsigned short* Xbf  = (unsigned short*)(ws + OFF_XBF);
  unsigned short* H2bf = (unsigned short*)(ws + OFF_H2BF);
  unsigned short* H1bf = (unsigned short*)(ws + OFF_H1BF);
  unsigned short* H1n  = (unsigned short*)(ws + OFF_H1N);
  float* Hp    = (float*)(ws + OFF_HP);
  float* h2s   = (float*)(ws + OFF_H2S);
  float* vb    = (float*)(ws + OFF_PV);
  float* slots = vb + 2 * 2 * 2048;
  float* sinv  = (float*)(ws + OFF_SINV);
  float* z2g   = (float*)(ws + OFF_Z2);
  float* Lg    = (float*)(ws + OFF_LC);
  float* alphag= (float*)(ws + OFF_AL);

  // gram-phase aliases
  unsigned short* W1T  = (unsigned short*)(ws + GOFF_W1T);
  unsigned short* Wp0  = (unsigned short*)(ws + GOFF_WP0);
  unsigned short* G1a  = (unsigned short*)(ws + GOFF_G1A);
  unsigned short* G1b  = (unsigned short*)(ws + GOFF_G1B);
  float*          Gpacc= (float*)(ws + GOFF_GPACC);
  unsigned short* W20  = (unsigned short*)(ws + GOFF_W20);
  unsigned short* G2c  = (unsigned short*)(ws + GOFF_G2C);
  unsigned short* G2d  = (unsigned short*)(ws + GOFF_G2D);
  // GP-phase aliases
  unsigned short* Hpb  = (unsigned short*)(ws + OFF_HPBF);
  unsigned short* zpad = (unsigned short*)(ws + OFF_ZPAD);
  float* logitsT = (float*)(ws + OFF_LGT);
  float* varT    = (float*)(ws + OFF_VART);

  float* out    = (float*)d_out;
  float* logits = out + (size_t)NB * NC;
  float* unc    = out + (size_t)2 * NB * NC;

  hipMemsetAsync(Hp, 0, (size_t)NB * NKF * 4, stream);
  hipMemsetAsync(Gpacc, 0, (size_t)NKF * NKF * 4, stream);

  // ---- spectral norms ----
  cast_bf<<<dim3(2048), 256, 0, stream>>>(W2, W20, NH * NH);
  cast_bf<<<dim3(128), 256, 0, stream>>>(Wp, Wp0, NKF * NH);
  transpose_cast<<<dim3(NE / 64, NH / 64), 256, 0, stream>>>(W1, W1T, NH, NE);
  gemm_nt<1><<<dim3(1, 1, 16), 256, 0, stream>>>(Wp0, Wp0, nullptr, (void*)Gpacc, NKF, NKF, NH, NH / 16, 1.0f);
  gp_power<<<dim3(1), 256, 0, stream>>>(Gpacc, sinv);
  gemm_nt<3><<<dim3(NE / 128, NE / 128), 256, 0, stream>>>(W1T, W1T, nullptr, (void*)G1a, NE, NE, NH, 0, 1.0f);
  gemm_nt<3><<<dim3(NH / 128, NH / 128), 256, 0, stream>>>(W20, W20, nullptr, (void*)G2c, NH, NH, NH, 0, 1.0f);
  gemm_nt<3><<<dim3(NE / 128, NE / 128), 256, 0, stream>>>(G1a, G1a, nullptr, (void*)G1b, NE, NE, NE, 0, 1.0f);
  gemm_nt<3><<<dim3(NH / 128, NH / 128), 256, 0, stream>>>(G2c, G2c, nullptr, (void*)G2d, NH, NH, NH, 0, 1.0f);
  gemm_nt<3><<<dim3(NE / 128, NE / 128), 256, 0, stream>>>(G1b, G1b, nullptr, (void*)G1a, NE, NE, NE, 0, 0.0625f);
  gemm_nt<3><<<dim3(NH / 128, NH / 128), 256, 0, stream>>>(G2d, G2d, nullptr, (void*)G2c, NH, NH, NH, 0, 0.0625f);
  init_gram<<<dim3(1), 256, 0, stream>>>(vb, slots);
  for (int i = 0; i < NITER_R; ++i)
    gram_iter<<<dim3(352), 256, 0, stream>>>(G1a, G2c, vb, slots, i);
  finalize_sigma<<<dim3(1), 64, 0, stream>>>(slots, sinv);
  scale_weights<<<dim3(2944), 256, 0, stream>>>(W1, W2, Wp, sinv, W1bf, W2bf, Wpbf);

  // ---- MLP ----
  ln_e<<<dim3(NB / 4), 256, 0, stream>>>(X, g1, be1, Xbf);
  gemm_nt<0><<<dim3(NB / 128, NH / 128), 256, 0, stream>>>(Xbf, W1bf, b1, (void*)H1bf, NB, NH, NE, 0, 1.0f);
  ln_h<<<dim3(NB / 4), 256, 0, stream>>>(H1bf, g2, be2, H1n);
  gemm_nt<0><<<dim3(NB / 128, NH / 128), 256, 0, stream>>>(H1n, W2bf, b2, (void*)H2bf, NB, NH, NH, 0, 1.0f);
  gemm_nt<1><<<dim3(NB / 128, 1, 8), 256, 0, stream>>>(H2bf, Wpbf, bp, (void*)Hp, NB, NKF, NH, NH / 8, 1.0f);
  finish_proj<<<dim3(NB / 4), 256, 0, stream>>>(Hp, bp, Hpb, h2s);

  // ---- GP head ----
  gp_prep<<<dim3(NC), 128, 0, stream>>>(Z, VM, ll, z2g, Lg, alphag, zpad);
  gp_main<<<dim3(NB / 256, NC), 256, 0, stream>>>(Hpb, h2s, zpad, z2g, Lg, alphag, ll, logitsT, varT);
  softmax_t<<<dim3(NB / 64), 256, 0, stream>>>(logitsT, varT, out, logits, unc);
}